// Round 13
// baseline (483.915 us; speedup 1.0000x reference)
//
#include <hip/hip_runtime.h>
#include <hip/hip_bf16.h>
#include <math.h>

#define NVEC 2000
#define DD   768
#define HH   1024
#define KNUM 250
#define MSEL 400
#define MR   399     // m-1 rows
#define OUTW 251
#define PPAD 256                 // padded antecedents per anaphor
#define NPAIR (MR * PPAD)        // 102144 padded pair rows
#define BM 256
#define BN 256
#define BK 64
#define NKT (DD / BK)            // 12
#define NNB (HH / BN)            // 4

typedef short  bf16x8 __attribute__((ext_vector_type(8)));
typedef float  f32x4  __attribute__((ext_vector_type(4)));
typedef unsigned int u32;
typedef u32    u32x4  __attribute__((ext_vector_type(4)));

__device__ __forceinline__ float waveSum(float p) {
#pragma unroll
  for (int off = 32; off >= 1; off >>= 1) p += __shfl_xor(p, off, 64);
  return p;
}
__device__ __forceinline__ float waveMax(float p) {
#pragma unroll
  for (int off = 32; off >= 1; off >>= 1) p = fmaxf(p, __shfl_xor(p, off, 64));
  return p;
}
__device__ __forceinline__ short f2bf(float f) {
  __hip_bfloat16 h = __float2bfloat16(f);     // RNE; pairs fuse to v_cvt_pk_bf16_f32
  return __builtin_bit_cast(short, h);
}
__device__ __forceinline__ void gload_lds16(const void* g, void* l) {
  __builtin_amdgcn_global_load_lds(
      (const __attribute__((address_space(1))) u32*)g,
      (__attribute__((address_space(3))) u32*)l, 16, 0, 0);
}
// x[e] = bf16( av[e] * f32(b[e]) )  -- 8-element chunk, in registers
__device__ __forceinline__ bf16x8 prodcvt(const float* av, bf16x8 b) {
  u32x4 u = __builtin_bit_cast(u32x4, b);
  bf16x8 r;
#pragma unroll
  for (int p = 0; p < 4; ++p) {
    const float blo = __builtin_bit_cast(float, u[p] << 16);
    const float bhi = __builtin_bit_cast(float, u[p] & 0xffff0000u);
    r[2 * p]     = f2bf(av[2 * p]     * blo);
    r[2 * p + 1] = f2bf(av[2 * p + 1] * bhi);
  }
  return r;
}

// ---------------- K1: scores = relu(V @ Wm1 + bm1) @ wm2 + bm2 ----------------
__global__ __launch_bounds__(512) void scores_kernel(
    const float* __restrict__ vectors, const float* __restrict__ Wm1,
    const float* __restrict__ bm1, const float* __restrict__ wm2,
    const float* __restrict__ bm2, float* __restrict__ scores) {
  __shared__ float vrow[8 * DD];
  __shared__ float red[8];
  const int tid = threadIdx.x;
  const int base = blockIdx.x * 8;
  for (int idx = tid; idx < 8 * DD; idx += 512)
    vrow[idx] = vectors[base * DD + idx];
  __syncthreads();
  float acc[8][2];
#pragma unroll
  for (int r = 0; r < 8; ++r) { acc[r][0] = 0.f; acc[r][1] = 0.f; }
#pragma unroll 4
  for (int d = 0; d < DD; ++d) {
    const float2 w = ((const float2*)(Wm1 + (size_t)d * HH))[tid];
#pragma unroll
    for (int r = 0; r < 8; ++r) {
      const float a = vrow[r * DD + d];
      acc[r][0] += a * w.x; acc[r][1] += a * w.y;
    }
  }
  const float2 b = ((const float2*)bm1)[tid];
  const float2 m = ((const float2*)wm2)[tid];
  const float sc = bm2[0];
  for (int r = 0; r < 8; ++r) {
    float p = fmaxf(acc[r][0] + b.x, 0.f) * m.x + fmaxf(acc[r][1] + b.y, 0.f) * m.y;
    p = waveSum(p);
    if ((tid & 63) == 0) red[tid >> 6] = p;
    __syncthreads();
    if (tid == 0) {
      float t = red[0];
#pragma unroll
      for (int w8 = 1; w8 < 8; ++w8) t += red[w8];
      scores[base + r] = t + sc;
    }
    __syncthreads();
  }
}

// ---------------- K2: bitonic sort (score desc, idx asc) -> top 400 ----------------
__global__ __launch_bounds__(1024) void topsort_kernel(
    const float* __restrict__ scores, int* __restrict__ top) {
  __shared__ float ks[2048];
  __shared__ int   ki[2048];
  const int tid = threadIdx.x;
  for (int e = tid; e < 2048; e += 1024) {
    ks[e] = (e < NVEC) ? scores[e] : -INFINITY;
    ki[e] = e;
  }
  __syncthreads();
  for (int k = 2; k <= 2048; k <<= 1) {
    for (int j = k >> 1; j > 0; j >>= 1) {
      for (int e = tid; e < 2048; e += 1024) {
        const int l = e ^ j;
        if (l > e) {
          const float s1 = ks[e], s2 = ks[l];
          const int i1 = ki[e], i2 = ki[l];
          const bool first = (s1 > s2) || (s1 == s2 && i1 < i2);
          const bool up = ((e & k) == 0);
          if (up ? !first : first) {
            ks[e] = s2; ks[l] = s1; ki[e] = i2; ki[l] = i1;
          }
        }
      }
      __syncthreads();
    }
  }
  if (tid < MSEL) top[tid] = ki[tid];
}

// ---------------- K3: lexsort by (start,end,pos) asc, reversed ----------------
__global__ __launch_bounds__(256) void lexsort_kernel(
    const int* __restrict__ top, const int* __restrict__ sst,
    const int* __restrict__ sen, const float* __restrict__ scores,
    int* __restrict__ perm, float* __restrict__ sfin) {
  __shared__ int s_st[512], s_en[512], s_j[512];
  const int tid = threadIdx.x;
  for (int e = tid; e < 512; e += 256) {
    if (e < MSEL) { const int ti = top[e]; s_st[e] = sst[ti]; s_en[e] = sen[ti]; }
    else { s_st[e] = 0x7fffffff; s_en[e] = 0x7fffffff; }
    s_j[e] = e;
  }
  __syncthreads();
  for (int k = 2; k <= 512; k <<= 1) {
    for (int j = k >> 1; j > 0; j >>= 1) {
      for (int e = tid; e < 512; e += 256) {
        const int l = e ^ j;
        if (l > e) {
          const int a0 = s_st[e], a1 = s_en[e], a2 = s_j[e];
          const int b0 = s_st[l], b1 = s_en[l], b2 = s_j[l];
          const bool first = (a0 < b0) || (a0 == b0 && (a1 < b1 || (a1 == b1 && a2 < b2)));
          const bool up = ((e & k) == 0);
          if (up ? !first : first) {
            s_st[e] = b0; s_en[e] = b1; s_j[e] = b2;
            s_st[l] = a0; s_en[l] = a1; s_j[l] = a2;
          }
        }
      }
      __syncthreads();
    }
  }
  for (int i = tid; i < MSEL; i += 256) {
    const int src = s_j[MSEL - 1 - i];
    const int vi = top[src];
    perm[i] = vi;
    sfin[i] = scores[vi];
  }
}

// ---------------- K4: Ha = v@Wa, Hv = v@Wb; gather Vp (f32) + Vpb (bf16) ----------------
__global__ __launch_bounds__(256) void hab_kernel(
    const float* __restrict__ vectors, const float* __restrict__ Wp1,
    const int* __restrict__ perm, float* __restrict__ Ha, float* __restrict__ Hv,
    float* __restrict__ Vp, ushort* __restrict__ Vpb) {
  __shared__ float vrow[8 * DD];
  const int tid = threadIdx.x;
  const int base = blockIdx.x * 8;
  const int mat = blockIdx.y >> 1;       // 0 = Wa, 1 = Wb
  const int half = blockIdx.y & 1;       // col half
  for (int r = 0; r < 8; ++r) {
    const int pi = perm[base + r];
    for (int d = tid; d < DD; d += 256) {
      const float val = vectors[pi * DD + d];
      vrow[r * DD + d] = val;
      if (blockIdx.y == 0) {
        Vp[(size_t)(base + r) * DD + d] = val;
        Vpb[(size_t)(base + r) * DD + d] = (ushort)f2bf(val);
      }
    }
  }
  __syncthreads();
  float acc[8][2];
#pragma unroll
  for (int r = 0; r < 8; ++r) { acc[r][0] = 0.f; acc[r][1] = 0.f; }
  const float* W = Wp1 + (size_t)mat * DD * HH + half * 512;
#pragma unroll 4
  for (int d = 0; d < DD; ++d) {
    const float2 w = ((const float2*)(W + (size_t)d * HH))[tid];
#pragma unroll
    for (int r = 0; r < 8; ++r) {
      const float a = vrow[r * DD + d];
      acc[r][0] += a * w.x; acc[r][1] += a * w.y;
    }
  }
  float* dst = mat ? Hv : Ha;
  for (int r = 0; r < 8; ++r) {
    const int row = base + r;
    if (mat == 0 && row >= MR) continue;
    ((float2*)(dst + (size_t)row * HH + half * 512))[tid] =
        make_float2(acc[r][0], acc[r][1]);
  }
}

// ---------------- K4b: Wt[n][k] = bf16(Wab[k][n]) (transpose + cast, once) ----------------
__global__ __launch_bounds__(256) void wt_kernel(
    const float* __restrict__ Wp1, ushort* __restrict__ Wt) {
  __shared__ float tile[64][65];
  const int kb = blockIdx.x;   // 12 tiles over K=768
  const int nb = blockIdx.y;   // 16 tiles over N=1024
  const float* Wab = Wp1 + 2 * DD * HH;
  for (int idx = threadIdx.x; idx < 64 * 64; idx += 256) {
    const int kk = idx >> 6, nn = idx & 63;
    tile[kk][nn] = Wab[(size_t)(kb * 64 + kk) * HH + nb * 64 + nn];
  }
  __syncthreads();
  for (int idx = threadIdx.x; idx < 64 * 64; idx += 256) {
    const int nn = idx >> 6, kk = idx & 63;
    Wt[(size_t)(nb * 64 + nn) * DD + kb * 64 + kk] = (ushort)f2bf(tile[kk][nn]);
  }
}

// ---------------- K5: pairwise einsum GEMM, 256x256, 8 waves, 8-phase schedule ----------------
// m201-style: per K-tile, 4 phases of {ds_read subtile || stage-slice issue ->
// s_barrier -> lgkmcnt(0) -> setprio(1) -> 16 MFMA -> setprio(0) -> s_barrier}.
// Staging for tile t+1 spread across phases; single vmcnt(0)+lgkmcnt(0) at the
// iteration boundary (DMAs are >=2 MFMA-phases old by then -> drain ~free).
// Within an iteration all writes target the nxt buffers, all reads cur -> race-free.
#define READ_BFR(KS)                                                         \
  {                                                                          \
    _Pragma("unroll")                                                        \
    for (int ni = 0; ni < 4; ++ni) {                                         \
      const int row = wc * 64 + ni * 16 + llo;                               \
      const int ch = ((KS) * 4 + lhi) ^ (row & 7);                           \
      bfr[ni] = *(const bf16x8*)((const char*)Bs[cur] + row * 128 + (ch << 4)); \
    }                                                                        \
  }
#define READ_AF(KS, MH)                                                      \
  {                                                                          \
    _Pragma("unroll")                                                        \
    for (int m = 0; m < 4; ++m) {                                            \
      const int row = wr * 128 + ((MH) * 4 + m) * 16 + llo;                  \
      const int ch = ((KS) * 4 + lhi) ^ (row & 7);                           \
      af[m] = *(const bf16x8*)((const char*)As[cur] + row * 128 + (ch << 4)); \
    }                                                                        \
  }
#define MFMA16(MH)                                                           \
  {                                                                          \
    _Pragma("unroll")                                                        \
    for (int m = 0; m < 4; ++m)                                              \
      _Pragma("unroll")                                                      \
      for (int ni = 0; ni < 4; ++ni)                                         \
        acc[(MH) * 4 + m][ni] = __builtin_amdgcn_mfma_f32_16x16x32_bf16(     \
            af[m], bfr[ni], acc[(MH) * 4 + m][ni], 0, 0, 0);                 \
  }
#define PHASE_MFMA(MH)                                                       \
  __builtin_amdgcn_s_barrier();                                              \
  asm volatile("s_waitcnt lgkmcnt(0)" ::: "memory");                         \
  __builtin_amdgcn_s_setprio(1);                                             \
  MFMA16(MH);                                                                \
  __builtin_amdgcn_s_setprio(0);

__global__ __launch_bounds__(512, 2) void pair_kernel(
    const float* __restrict__ Vp, const ushort* __restrict__ Vpb,
    const ushort* __restrict__ Wt,
    const float* __restrict__ bp1, const float* __restrict__ wp2,
    const float* __restrict__ Ha, const float* __restrict__ Hv,
    float* __restrict__ pp) {
  __shared__ __align__(16) ushort As[2][BM * BK];   // 2 x 32 KB
  __shared__ __align__(16) ushort Bs[2][BN * BK];   // 2 x 32 KB
  __shared__ float redp[BM][4];
  const int tid = threadIdx.x;
  const int i = blockIdx.x;           // 0..398
  const int nb = blockIdx.y;          // 0..3
  const int n0 = nb * BN;
  const int lane = tid & 63;
  const int wid = tid >> 6;           // 0..7
  const int wr = wid >> 2, wc = wid & 3;
  const int lhi = lane >> 4, llo = lane & 15;

  // ---- stage geometry ----
  const int cs = tid & 7;
  const int rbase = tid >> 3;                 // 0..63
  const int csx = cs ^ (rbase & 7);
  const ushort* vsrc[4];
  int rowA[4];
#pragma unroll
  for (int it = 0; it < 4; ++it) {
    rowA[it] = it * 64 + rbase;
    int j = i + 1 + rowA[it];
    if (j > MR) j = MR;
    vsrc[it] = Vpb + (size_t)j * DD + cs * 8;
  }
  const float* avp = Vp + (size_t)i * DD + cs * 8;   // L1-hot row i

  f32x4 acc[8][4];
#pragma unroll
  for (int a = 0; a < 8; ++a)
#pragma unroll
    for (int b = 0; b < 4; ++b) acc[a][b] = (f32x4){0.f, 0.f, 0.f, 0.f};

  // ---- prologue: stage tile 0 into buffers [0] ----
  {
    float av0[8];
    *(float4*)(av0) = *(const float4*)(avp);
    *(float4*)(av0 + 4) = *(const float4*)(avp + 4);
    bf16x8 b0 = *(const bf16x8*)(vsrc[0]);
    bf16x8 b1 = *(const bf16x8*)(vsrc[1]);
    bf16x8 b2 = *(const bf16x8*)(vsrc[2]);
    bf16x8 b3 = *(const bf16x8*)(vsrc[3]);
#pragma unroll
    for (int it = 0; it < 4; ++it)
      gload_lds16(Wt + (size_t)(n0 + rowA[it]) * DD + csx * 8,
                  (char*)Bs[0] + (it * 512 + tid) * 16);
    *(bf16x8*)((char*)As[0] + rowA[0] * 128 + (csx << 4)) = prodcvt(av0, b0);
    *(bf16x8*)((char*)As[0] + rowA[1] * 128 + (csx << 4)) = prodcvt(av0, b1);
    *(bf16x8*)((char*)As[0] + rowA[2] * 128 + (csx << 4)) = prodcvt(av0, b2);
    *(bf16x8*)((char*)As[0] + rowA[3] * 128 + (csx << 4)) = prodcvt(av0, b3);
  }
  __syncthreads();

  int cur = 0;
  for (int t = 0; t < NKT; ++t) {
    const int nxt = cur ^ 1;
    const bool hn = (t + 1 < NKT);
    const int kg1 = (t + 1) * BK;
    bf16x8 af[4], bfr[4];
    bf16x8 bv0a, bv0b, bv1a, bv1b;
    float av[8];

    // ---- P0: reads bfr(ks0)+af(ks0,mh0); stage B-DMA slice0 + av ----
    READ_BFR(0)
    READ_AF(0, 0)
    if (hn) {
      gload_lds16(Wt + (size_t)(n0 + rowA[0]) * DD + kg1 + csx * 8,
                  (char*)Bs[nxt] + (0 * 512 + tid) * 16);
      gload_lds16(Wt + (size_t)(n0 + rowA[1]) * DD + kg1 + csx * 8,
                  (char*)Bs[nxt] + (1 * 512 + tid) * 16);
      *(float4*)(av) = *(const float4*)(avp + kg1);
      *(float4*)(av + 4) = *(const float4*)(avp + kg1 + 4);
    }
    PHASE_MFMA(0)
    __builtin_amdgcn_s_barrier();

    // ---- P1: reads af(ks0,mh1); stage B-DMA slice1 + bv slice0 ----
    READ_AF(0, 1)
    if (hn) {
      gload_lds16(Wt + (size_t)(n0 + rowA[2]) * DD + kg1 + csx * 8,
                  (char*)Bs[nxt] + (2 * 512 + tid) * 16);
      gload_lds16(Wt + (size_t)(n0 + rowA[3]) * DD + kg1 + csx * 8,
                  (char*)Bs[nxt] + (3 * 512 + tid) * 16);
      bv0a = *(const bf16x8*)(vsrc[0] + kg1);
      bv0b = *(const bf16x8*)(vsrc[1] + kg1);
    }
    PHASE_MFMA(1)
    __builtin_amdgcn_s_barrier();

    // ---- P2: reads bfr(ks1)+af(ks1,mh0); stage bv slice1 + A-write slice0 ----
    READ_BFR(1)
    READ_AF(1, 0)
    if (hn) {
      bv1a = *(const bf16x8*)(vsrc[2] + kg1);
      bv1b = *(const bf16x8*)(vsrc[3] + kg1);
      *(bf16x8*)((char*)As[nxt] + rowA[0] * 128 + (csx << 4)) = prodcvt(av, bv0a);
      *(bf16x8*)((char*)As[nxt] + rowA[1] * 128 + (csx << 4)) = prodcvt(av, bv0b);
    }
    PHASE_MFMA(0)
    __builtin_amdgcn_s_barrier();

    // ---- P3: reads af(ks1,mh1); stage A-write slice1 ----
    READ_AF(1, 1)
    if (hn) {
      *(bf16x8*)((char*)As[nxt] + rowA[2] * 128 + (csx << 4)) = prodcvt(av, bv1a);
      *(bf16x8*)((char*)As[nxt] + rowA[3] * 128 + (csx << 4)) = prodcvt(av, bv1b);
    }
    PHASE_MFMA(1)
    // ---- iteration boundary: full drain (DMAs >=2 phases old) + barrier ----
    asm volatile("s_waitcnt vmcnt(0) lgkmcnt(0)" ::: "memory");
    __builtin_amdgcn_s_barrier();
    cur = nxt;
  }

  // ---- epilogue: relu(acc + Ha_i + Hv_j + bp1) . wp2 over this wave's 64 cols ----
  float hb4[4], wpv[4];
  int cg[4];
#pragma unroll
  for (int ni = 0; ni < 4; ++ni) {
    const int col = n0 + wc * 64 + ni * 16 + llo;
    cg[ni] = col;
    hb4[ni] = Ha[(size_t)i * HH + col] + bp1[col];
    wpv[ni] = wp2[col];
  }
#pragma unroll
  for (int mi = 0; mi < 8; ++mi) {
#pragma unroll
    for (int r = 0; r < 4; ++r) {
      const int rowl = wr * 128 + mi * 16 + lhi * 4 + r;
      int j = i + 1 + rowl;
      if (j > MR) j = MR;
      float part = 0.f;
#pragma unroll
      for (int ni = 0; ni < 4; ++ni) {
        const float pre = acc[mi][ni][r] + hb4[ni] + Hv[(size_t)j * HH + cg[ni]];
        part += fmaxf(pre, 0.f) * wpv[ni];
      }
      part += __shfl_xor(part, 1, 64);
      part += __shfl_xor(part, 2, 64);
      part += __shfl_xor(part, 4, 64);
      part += __shfl_xor(part, 8, 64);
      if (llo == 0) redp[rowl][wc] = part;   // per-wave column-quarter partial
    }
  }
  __syncthreads();
  if (tid < BM)
    pp[(size_t)nb * NPAIR + (size_t)i * PPAD + tid] =
        redp[tid][0] + redp[tid][1] + redp[tid][2] + redp[tid][3];
}

// ---------------- K6: sum partials + bias + scores, mask, softmax over 251 ----------------
__global__ __launch_bounds__(256) void softmax_kernel(
    const float* __restrict__ pp, const float* __restrict__ sfin,
    const float* __restrict__ bp2, float* __restrict__ out) {
  __shared__ float red[4];
  const int i = blockIdx.x, tid = threadIdx.x;
  float v;
  if (tid < KNUM) {
    const int jidx = i + 1 + tid;
    const bool valid = jidx < MSEL;
    const int jc = valid ? jidx : MR;
    float s = 0.f;
#pragma unroll
    for (int b = 0; b < NNB; ++b) s += pp[(size_t)b * NPAIR + i * PPAD + tid];
    v = valid ? (s + bp2[0] + sfin[jc] + sfin[i]) : -INFINITY;
  } else if (tid == KNUM) v = 0.f;
  else v = -INFINITY;
  float mx = waveMax(v);
  if ((tid & 63) == 0) red[tid >> 6] = mx;
  __syncthreads();
  const float m = fmaxf(fmaxf(red[0], red[1]), fmaxf(red[2], red[3]));
  __syncthreads();
  const float e = (tid <= KNUM) ? expf(v - m) : 0.f;
  float s = waveSum(e);
  if ((tid & 63) == 0) red[tid >> 6] = s;
  __syncthreads();
  const float tot = red[0] + red[1] + red[2] + red[3];
  if (tid <= KNUM) out[i * OUTW + tid] = e / tot;
}

extern "C" void kernel_launch(void* const* d_in, const int* in_sizes, int n_in,
                              void* d_out, int out_size, void* d_ws, size_t ws_size,
                              hipStream_t stream) {
  const float* vectors = (const float*)d_in[0];
  const float* Wm1 = (const float*)d_in[1];
  const float* bm1 = (const float*)d_in[2];
  const float* wm2 = (const float*)d_in[3];
  const float* bm2 = (const float*)d_in[4];
  const float* Wp1 = (const float*)d_in[5];
  const float* bp1 = (const float*)d_in[6];
  const float* wp2 = (const float*)d_in[7];
  const float* bp2 = (const float*)d_in[8];
  const int* sst = (const int*)d_in[9];
  const int* sen = (const int*)d_in[10];
  float* out = (float*)d_out;
  char* ws = (char*)d_ws;

  float* scores = (float*)(ws);                          // 2000 f32
  int*   top    = (int*)(ws + 8192);                     // 400 i32
  int*   perm   = (int*)(ws + 10240);                    // 400 i32
  float* sfin   = (float*)(ws + 12288);                  // 400 f32
  float* Ha     = (float*)(ws + 16384);                  // 400*1024 f32
  float* Hv     = (float*)(ws + 16384 + 1638400);        // 400*1024 f32
  float* Vp     = (float*)(ws + 3293184);                // 400*768 f32
  ushort* Wt    = (ushort*)(ws + 4521984);               // 1024*768 bf16
  ushort* Vpb   = (ushort*)(ws + 6094848);               // 400*768 bf16
  float* pp     = (float*)(ws + 6709248);                // 4 * 102144 f32 partials

  scores_kernel<<<NVEC / 8, 512, 0, stream>>>(vectors, Wm1, bm1, wm2, bm2, scores);
  topsort_kernel<<<1, 1024, 0, stream>>>(scores, top);
  lexsort_kernel<<<1, 256, 0, stream>>>(top, sst, sen, scores, perm, sfin);
  wt_kernel<<<dim3(12, 16), 256, 0, stream>>>(Wp1, Wt);
  hab_kernel<<<dim3(MSEL / 8, 4), 256, 0, stream>>>(vectors, Wp1, perm, Ha, Hv, Vp, Vpb);
  pair_kernel<<<dim3(MR, NNB), 512, 0, stream>>>(Vp, Vpb, Wt, bp1, wp2, Ha, Hv, pp);
  softmax_kernel<<<MR, 256, 0, stream>>>(pp, sfin, bp2, out);
}

// Round 14
// 418.485 us; speedup vs baseline: 1.1564x; 1.1564x over previous
//
#include <hip/hip_runtime.h>
#include <hip/hip_bf16.h>
#include <math.h>

#define NVEC 2000
#define DD   768
#define HH   1024
#define KNUM 250
#define MSEL 400
#define MR   399     // m-1 rows
#define OUTW 251
#define PPAD 256                 // padded antecedents per anaphor
#define NPAIR (MR * PPAD)        // 102144 padded pair rows
#define BM 128
#define BN 128
#define BK 64
#define NKT (DD / BK)            // 12
#define NNB (HH / BN)            // 8

typedef short  bf16x8 __attribute__((ext_vector_type(8)));
typedef float  f32x4  __attribute__((ext_vector_type(4)));
typedef unsigned int u32;
typedef u32    u32x4  __attribute__((ext_vector_type(4)));

__device__ __forceinline__ float waveSum(float p) {
#pragma unroll
  for (int off = 32; off >= 1; off >>= 1) p += __shfl_xor(p, off, 64);
  return p;
}
__device__ __forceinline__ float waveMax(float p) {
#pragma unroll
  for (int off = 32; off >= 1; off >>= 1) p = fmaxf(p, __shfl_xor(p, off, 64));
  return p;
}
__device__ __forceinline__ short f2bf(float f) {
  __hip_bfloat16 h = __float2bfloat16(f);     // RNE; pairs fuse to v_cvt_pk_bf16_f32
  return __builtin_bit_cast(short, h);
}
__device__ __forceinline__ void gload_lds16(const void* g, void* l) {
  __builtin_amdgcn_global_load_lds(
      (const __attribute__((address_space(1))) u32*)g,
      (__attribute__((address_space(3))) u32*)l, 16, 0, 0);
}
// x[e] = bf16( av[e] * f32(b[e]) )  -- 8-element chunk, in registers
__device__ __forceinline__ bf16x8 prodcvt(const float* av, bf16x8 b) {
  u32x4 u = __builtin_bit_cast(u32x4, b);
  bf16x8 r;
#pragma unroll
  for (int p = 0; p < 4; ++p) {
    const float blo = __builtin_bit_cast(float, u[p] << 16);
    const float bhi = __builtin_bit_cast(float, u[p] & 0xffff0000u);
    r[2 * p]     = f2bf(av[2 * p]     * blo);
    r[2 * p + 1] = f2bf(av[2 * p + 1] * bhi);
  }
  return r;
}

// ---------------- K1: scores = relu(V @ Wm1 + bm1) @ wm2 + bm2 ----------------
__global__ __launch_bounds__(512) void scores_kernel(
    const float* __restrict__ vectors, const float* __restrict__ Wm1,
    const float* __restrict__ bm1, const float* __restrict__ wm2,
    const float* __restrict__ bm2, float* __restrict__ scores) {
  __shared__ float vrow[8 * DD];
  __shared__ float red[8];
  const int tid = threadIdx.x;
  const int base = blockIdx.x * 8;
  for (int idx = tid; idx < 8 * DD; idx += 512)
    vrow[idx] = vectors[base * DD + idx];
  __syncthreads();
  float acc[8][2];
#pragma unroll
  for (int r = 0; r < 8; ++r) { acc[r][0] = 0.f; acc[r][1] = 0.f; }
#pragma unroll 4
  for (int d = 0; d < DD; ++d) {
    const float2 w = ((const float2*)(Wm1 + (size_t)d * HH))[tid];
#pragma unroll
    for (int r = 0; r < 8; ++r) {
      const float a = vrow[r * DD + d];
      acc[r][0] += a * w.x; acc[r][1] += a * w.y;
    }
  }
  const float2 b = ((const float2*)bm1)[tid];
  const float2 m = ((const float2*)wm2)[tid];
  const float sc = bm2[0];
  for (int r = 0; r < 8; ++r) {
    float p = fmaxf(acc[r][0] + b.x, 0.f) * m.x + fmaxf(acc[r][1] + b.y, 0.f) * m.y;
    p = waveSum(p);
    if ((tid & 63) == 0) red[tid >> 6] = p;
    __syncthreads();
    if (tid == 0) {
      float t = red[0];
#pragma unroll
      for (int w8 = 1; w8 < 8; ++w8) t += red[w8];
      scores[base + r] = t + sc;
    }
    __syncthreads();
  }
}

// ---------------- K2: bitonic sort (score desc, idx asc) -> top 400 ----------------
__global__ __launch_bounds__(1024) void topsort_kernel(
    const float* __restrict__ scores, int* __restrict__ top) {
  __shared__ float ks[2048];
  __shared__ int   ki[2048];
  const int tid = threadIdx.x;
  for (int e = tid; e < 2048; e += 1024) {
    ks[e] = (e < NVEC) ? scores[e] : -INFINITY;
    ki[e] = e;
  }
  __syncthreads();
  for (int k = 2; k <= 2048; k <<= 1) {
    for (int j = k >> 1; j > 0; j >>= 1) {
      for (int e = tid; e < 2048; e += 1024) {
        const int l = e ^ j;
        if (l > e) {
          const float s1 = ks[e], s2 = ks[l];
          const int i1 = ki[e], i2 = ki[l];
          const bool first = (s1 > s2) || (s1 == s2 && i1 < i2);
          const bool up = ((e & k) == 0);
          if (up ? !first : first) {
            ks[e] = s2; ks[l] = s1; ki[e] = i2; ki[l] = i1;
          }
        }
      }
      __syncthreads();
    }
  }
  if (tid < MSEL) top[tid] = ki[tid];
}

// ---------------- K3: lexsort by (start,end,pos) asc, reversed ----------------
__global__ __launch_bounds__(256) void lexsort_kernel(
    const int* __restrict__ top, const int* __restrict__ sst,
    const int* __restrict__ sen, const float* __restrict__ scores,
    int* __restrict__ perm, float* __restrict__ sfin) {
  __shared__ int s_st[512], s_en[512], s_j[512];
  const int tid = threadIdx.x;
  for (int e = tid; e < 512; e += 256) {
    if (e < MSEL) { const int ti = top[e]; s_st[e] = sst[ti]; s_en[e] = sen[ti]; }
    else { s_st[e] = 0x7fffffff; s_en[e] = 0x7fffffff; }
    s_j[e] = e;
  }
  __syncthreads();
  for (int k = 2; k <= 512; k <<= 1) {
    for (int j = k >> 1; j > 0; j >>= 1) {
      for (int e = tid; e < 512; e += 256) {
        const int l = e ^ j;
        if (l > e) {
          const int a0 = s_st[e], a1 = s_en[e], a2 = s_j[e];
          const int b0 = s_st[l], b1 = s_en[l], b2 = s_j[l];
          const bool first = (a0 < b0) || (a0 == b0 && (a1 < b1 || (a1 == b1 && a2 < b2)));
          const bool up = ((e & k) == 0);
          if (up ? !first : first) {
            s_st[e] = b0; s_en[e] = b1; s_j[e] = b2;
            s_st[l] = a0; s_en[l] = a1; s_j[l] = a2;
          }
        }
      }
      __syncthreads();
    }
  }
  for (int i = tid; i < MSEL; i += 256) {
    const int src = s_j[MSEL - 1 - i];
    const int vi = top[src];
    perm[i] = vi;
    sfin[i] = scores[vi];
  }
}

// ---------------- K4: Ha = v@Wa, Hv = v@Wb; gather Vp (f32) + Vpb (bf16) ----------------
__global__ __launch_bounds__(256) void hab_kernel(
    const float* __restrict__ vectors, const float* __restrict__ Wp1,
    const int* __restrict__ perm, float* __restrict__ Ha, float* __restrict__ Hv,
    float* __restrict__ Vp, ushort* __restrict__ Vpb) {
  __shared__ float vrow[8 * DD];
  const int tid = threadIdx.x;
  const int base = blockIdx.x * 8;
  const int mat = blockIdx.y >> 1;       // 0 = Wa, 1 = Wb
  const int half = blockIdx.y & 1;       // col half
  for (int r = 0; r < 8; ++r) {
    const int pi = perm[base + r];
    for (int d = tid; d < DD; d += 256) {
      const float val = vectors[pi * DD + d];
      vrow[r * DD + d] = val;
      if (blockIdx.y == 0) {
        Vp[(size_t)(base + r) * DD + d] = val;
        Vpb[(size_t)(base + r) * DD + d] = (ushort)f2bf(val);
      }
    }
  }
  __syncthreads();
  float acc[8][2];
#pragma unroll
  for (int r = 0; r < 8; ++r) { acc[r][0] = 0.f; acc[r][1] = 0.f; }
  const float* W = Wp1 + (size_t)mat * DD * HH + half * 512;
#pragma unroll 4
  for (int d = 0; d < DD; ++d) {
    const float2 w = ((const float2*)(W + (size_t)d * HH))[tid];
#pragma unroll
    for (int r = 0; r < 8; ++r) {
      const float a = vrow[r * DD + d];
      acc[r][0] += a * w.x; acc[r][1] += a * w.y;
    }
  }
  float* dst = mat ? Hv : Ha;
  for (int r = 0; r < 8; ++r) {
    const int row = base + r;
    if (mat == 0 && row >= MR) continue;
    ((float2*)(dst + (size_t)row * HH + half * 512))[tid] =
        make_float2(acc[r][0], acc[r][1]);
  }
}

// ---------------- K4b: Wt[n][k] = bf16(Wab[k][n]) (transpose + cast, once) ----------------
__global__ __launch_bounds__(256) void wt_kernel(
    const float* __restrict__ Wp1, ushort* __restrict__ Wt) {
  __shared__ float tile[64][65];
  const int kb = blockIdx.x;   // 12 tiles over K=768
  const int nb = blockIdx.y;   // 16 tiles over N=1024
  const float* Wab = Wp1 + 2 * DD * HH;
  for (int idx = threadIdx.x; idx < 64 * 64; idx += 256) {
    const int kk = idx >> 6, nn = idx & 63;
    tile[kk][nn] = Wab[(size_t)(kb * 64 + kk) * HH + nb * 64 + nn];
  }
  __syncthreads();
  for (int idx = threadIdx.x; idx < 64 * 64; idx += 256) {
    const int nn = idx >> 6, kk = idx & 63;
    Wt[(size_t)(nb * 64 + nn) * DD + kb * 64 + kk] = (ushort)f2bf(tile[kk][nn]);
  }
}

// ---------------- K5: pairwise einsum GEMM, 128x128 tile, 4 waves, 4 blocks/CU ----------------
// Occupancy-first: acc[4][4] = 64 AGPR + ~60 VGPR <= 128 total -> 16 waves/CU =
// 4 independent blocks/CU. Cross-block overlap (m97/m114) hides each block's
// stage+barrier under another block's MFMA. Same verified swizzle/fragment/DMA
// paths as r12, at the r3-proven 128^2 geometry. LDS 33 KB/block.
__global__ __launch_bounds__(256, 4) void pair_kernel(
    const float* __restrict__ Vp, const ushort* __restrict__ Vpb,
    const ushort* __restrict__ Wt,
    const float* __restrict__ bp1, const float* __restrict__ wp2,
    const float* __restrict__ Ha, const float* __restrict__ Hv,
    float* __restrict__ pp) {
  __shared__ __align__(16) ushort As[BM * BK];      // 16 KB
  __shared__ __align__(16) ushort Bs[BN * BK];      // 16 KB
  __shared__ float redp[BM][2];                     // 1 KB
  const int tid = threadIdx.x;
  const int mb = blockIdx.x;          // 0..797  (i*2 + khalf)
  const int nb = blockIdx.y;          // 0..7
  const int i = mb >> 1;
  const int khalf = mb & 1;
  const int n0 = nb * BN;
  const int lane = tid & 63;
  const int wid = tid >> 6;           // 0..3
  const int wr = wid >> 1, wc = wid & 1;
  const int lhi = lane >> 4, llo = lane & 15;

  // ---- stage geometry: 4 chunks/thread; cs and swizzled slot constant ----
  const int cs = tid & 7;
  const int rb8 = tid >> 3;                   // 0..31
  const int csx = cs ^ (rb8 & 7);             // same for all 4 chunks
  const ushort* vsrc[4];
  int rowA[4];
#pragma unroll
  for (int it = 0; it < 4; ++it) {
    rowA[it] = it * 32 + rb8;                 // 0..127
    int j = i + 1 + khalf * BM + rowA[it];
    if (j > MR) j = MR;
    vsrc[it] = Vpb + (size_t)j * DD + cs * 8;
  }
  const float* avp = Vp + (size_t)i * DD + cs * 8;   // L1-hot row i

  f32x4 acc[4][4];
#pragma unroll
  for (int a = 0; a < 4; ++a)
#pragma unroll
    for (int b = 0; b < 4; ++b) acc[a][b] = (f32x4){0.f, 0.f, 0.f, 0.f};

  for (int kt = 0; kt < NKT; ++kt) {
    const int kg = kt * BK;
    // ---- stage phase: A-src loads FIRST (oldest VMEM), then B-DMAs, then prodcvt ----
    bf16x8 bv[4];
    float av[8];
#pragma unroll
    for (int it = 0; it < 4; ++it) bv[it] = *(const bf16x8*)(vsrc[it] + kg);
    *(float4*)(av) = *(const float4*)(avp + kg);
    *(float4*)(av + 4) = *(const float4*)(avp + kg + 4);
#pragma unroll
    for (int it = 0; it < 4; ++it)
      gload_lds16(Wt + (size_t)(n0 + rowA[it]) * DD + kg + csx * 8,
                  (char*)Bs + (it * 256 + tid) * 16);
#pragma unroll
    for (int it = 0; it < 4; ++it)
      *(bf16x8*)((char*)As + rowA[it] * 128 + (csx << 4)) = prodcvt(av, bv[it]);
    __syncthreads();   // drains DMA writes + A ds_writes
    // ---- compute phase: 2 k-steps of 32; 4x4 fragments per wave ----
#pragma unroll
    for (int ks = 0; ks < 2; ++ks) {
      bf16x8 af[4], bfr[4];
#pragma unroll
      for (int mi = 0; mi < 4; ++mi) {
        const int row = wr * 64 + mi * 16 + llo;
        const int ch = (ks * 4 + lhi) ^ (row & 7);
        af[mi] = *(const bf16x8*)((const char*)As + row * 128 + (ch << 4));
      }
#pragma unroll
      for (int ni = 0; ni < 4; ++ni) {
        const int row = wc * 64 + ni * 16 + llo;
        const int ch = (ks * 4 + lhi) ^ (row & 7);
        bfr[ni] = *(const bf16x8*)((const char*)Bs + row * 128 + (ch << 4));
      }
#pragma unroll
      for (int mi = 0; mi < 4; ++mi)
#pragma unroll
        for (int ni = 0; ni < 4; ++ni)
          acc[mi][ni] = __builtin_amdgcn_mfma_f32_16x16x32_bf16(af[mi], bfr[ni], acc[mi][ni], 0, 0, 0);
    }
    __syncthreads();   // all reads done before next stage overwrites
  }

  // ---- epilogue: relu(acc + Ha_i + Hv_j + bp1) . wp2 over this wave's 64 cols ----
  float hb4[4], wpv[4];
  int cg[4];
#pragma unroll
  for (int ni = 0; ni < 4; ++ni) {
    const int col = n0 + wc * 64 + ni * 16 + llo;
    cg[ni] = col;
    hb4[ni] = Ha[(size_t)i * HH + col] + bp1[col];
    wpv[ni] = wp2[col];
  }
#pragma unroll
  for (int mi = 0; mi < 4; ++mi) {
#pragma unroll
    for (int r = 0; r < 4; ++r) {
      const int rowl = wr * 64 + mi * 16 + lhi * 4 + r;
      int j = i + 1 + khalf * BM + rowl;
      if (j > MR) j = MR;
      float part = 0.f;
#pragma unroll
      for (int ni = 0; ni < 4; ++ni) {
        const float pre = acc[mi][ni][r] + hb4[ni] + Hv[(size_t)j * HH + cg[ni]];
        part += fmaxf(pre, 0.f) * wpv[ni];
      }
      part += __shfl_xor(part, 1, 64);
      part += __shfl_xor(part, 2, 64);
      part += __shfl_xor(part, 4, 64);
      part += __shfl_xor(part, 8, 64);
      if (llo == 0) redp[rowl][wc] = part;   // per-wave column-half partial
    }
  }
  __syncthreads();
  if (tid < BM)
    pp[(size_t)nb * NPAIR + (size_t)i * PPAD + khalf * BM + tid] =
        redp[tid][0] + redp[tid][1];
}

// ---------------- K6: sum partials + bias + scores, mask, softmax over 251 ----------------
__global__ __launch_bounds__(256) void softmax_kernel(
    const float* __restrict__ pp, const float* __restrict__ sfin,
    const float* __restrict__ bp2, float* __restrict__ out) {
  __shared__ float red[4];
  const int i = blockIdx.x, tid = threadIdx.x;
  float v;
  if (tid < KNUM) {
    const int jidx = i + 1 + tid;
    const bool valid = jidx < MSEL;
    const int jc = valid ? jidx : MR;
    float s = 0.f;
#pragma unroll
    for (int b = 0; b < NNB; ++b) s += pp[(size_t)b * NPAIR + i * PPAD + tid];
    v = valid ? (s + bp2[0] + sfin[jc] + sfin[i]) : -INFINITY;
  } else if (tid == KNUM) v = 0.f;
  else v = -INFINITY;
  float mx = waveMax(v);
  if ((tid & 63) == 0) red[tid >> 6] = mx;
  __syncthreads();
  const float m = fmaxf(fmaxf(red[0], red[1]), fmaxf(red[2], red[3]));
  __syncthreads();
  const float e = (tid <= KNUM) ? expf(v - m) : 0.f;
  float s = waveSum(e);
  if ((tid & 63) == 0) red[tid >> 6] = s;
  __syncthreads();
  const float tot = red[0] + red[1] + red[2] + red[3];
  if (tid <= KNUM) out[i * OUTW + tid] = e / tot;
}

extern "C" void kernel_launch(void* const* d_in, const int* in_sizes, int n_in,
                              void* d_out, int out_size, void* d_ws, size_t ws_size,
                              hipStream_t stream) {
  const float* vectors = (const float*)d_in[0];
  const float* Wm1 = (const float*)d_in[1];
  const float* bm1 = (const float*)d_in[2];
  const float* wm2 = (const float*)d_in[3];
  const float* bm2 = (const float*)d_in[4];
  const float* Wp1 = (const float*)d_in[5];
  const float* bp1 = (const float*)d_in[6];
  const float* wp2 = (const float*)d_in[7];
  const float* bp2 = (const float*)d_in[8];
  const int* sst = (const int*)d_in[9];
  const int* sen = (const int*)d_in[10];
  float* out = (float*)d_out;
  char* ws = (char*)d_ws;

  float* scores = (float*)(ws);                          // 2000 f32
  int*   top    = (int*)(ws + 8192);                     // 400 i32
  int*   perm   = (int*)(ws + 10240);                    // 400 i32
  float* sfin   = (float*)(ws + 12288);                  // 400 f32
  float* Ha     = (float*)(ws + 16384);                  // 400*1024 f32
  float* Hv     = (float*)(ws + 16384 + 1638400);        // 400*1024 f32
  float* Vp     = (float*)(ws + 3293184);                // 400*768 f32
  ushort* Wt    = (ushort*)(ws + 4521984);               // 1024*768 bf16
  ushort* Vpb   = (ushort*)(ws + 6094848);               // 400*768 bf16
  float* pp     = (float*)(ws + 6709248);                // 8 * 102144 f32 partials

  scores_kernel<<<NVEC / 8, 512, 0, stream>>>(vectors, Wm1, bm1, wm2, bm2, scores);
  topsort_kernel<<<1, 1024, 0, stream>>>(scores, top);
  lexsort_kernel<<<1, 256, 0, stream>>>(top, sst, sen, scores, perm, sfin);
  wt_kernel<<<dim3(12, 16), 256, 0, stream>>>(Wp1, Wt);
  hab_kernel<<<dim3(MSEL / 8, 4), 256, 0, stream>>>(vectors, Wp1, perm, Ha, Hv, Vp, Vpb);
  pair_kernel<<<dim3(MR * 2, NNB), 256, 0, stream>>>(Vp, Vpb, Wt, bp1, wp2, Ha, Hv, pp);
  softmax_kernel<<<MR, 256, 0, stream>>>(pp, sfin, bp2, out);
}

// Round 15
// 405.486 us; speedup vs baseline: 1.1934x; 1.0321x over previous
//
#include <hip/hip_runtime.h>
#include <hip/hip_bf16.h>
#include <math.h>

#define NVEC 2000
#define DD   768
#define HH   1024
#define KNUM 250
#define MSEL 400
#define MR   399     // m-1 rows
#define OUTW 251
#define PPAD 256                 // padded antecedents per anaphor
#define NPAIR (MR * PPAD)        // 102144 padded pair rows
#define BM 128
#define BN 256
#define BK 64
#define NKT (DD / BK)            // 12
#define NNB (HH / BN)            // 4

typedef short  bf16x8 __attribute__((ext_vector_type(8)));
typedef float  f32x4  __attribute__((ext_vector_type(4)));
typedef unsigned int u32;
typedef u32    u32x4  __attribute__((ext_vector_type(4)));

__device__ __forceinline__ float waveSum(float p) {
#pragma unroll
  for (int off = 32; off >= 1; off >>= 1) p += __shfl_xor(p, off, 64);
  return p;
}
__device__ __forceinline__ float waveMax(float p) {
#pragma unroll
  for (int off = 32; off >= 1; off >>= 1) p = fmaxf(p, __shfl_xor(p, off, 64));
  return p;
}
__device__ __forceinline__ short f2bf(float f) {
  __hip_bfloat16 h = __float2bfloat16(f);     // RNE; pairs fuse to v_cvt_pk_bf16_f32
  return __builtin_bit_cast(short, h);
}
__device__ __forceinline__ void gload_lds16(const void* g, void* l) {
  __builtin_amdgcn_global_load_lds(
      (const __attribute__((address_space(1))) u32*)g,
      (__attribute__((address_space(3))) u32*)l, 16, 0, 0);
}
// x[e] = bf16( av[e] * f32(b[e]) )  -- 8-element chunk, in registers
__device__ __forceinline__ bf16x8 prodcvt(const float* av, bf16x8 b) {
  u32x4 u = __builtin_bit_cast(u32x4, b);
  bf16x8 r;
#pragma unroll
  for (int p = 0; p < 4; ++p) {
    const float blo = __builtin_bit_cast(float, u[p] << 16);
    const float bhi = __builtin_bit_cast(float, u[p] & 0xffff0000u);
    r[2 * p]     = f2bf(av[2 * p]     * blo);
    r[2 * p + 1] = f2bf(av[2 * p + 1] * bhi);
  }
  return r;
}

// ---------------- K1: scores = relu(V @ Wm1 + bm1) @ wm2 + bm2 ----------------
__global__ __launch_bounds__(512) void scores_kernel(
    const float* __restrict__ vectors, const float* __restrict__ Wm1,
    const float* __restrict__ bm1, const float* __restrict__ wm2,
    const float* __restrict__ bm2, float* __restrict__ scores) {
  __shared__ float vrow[8 * DD];
  __shared__ float red[8];
  const int tid = threadIdx.x;
  const int base = blockIdx.x * 8;
  for (int idx = tid; idx < 8 * DD; idx += 512)
    vrow[idx] = vectors[base * DD + idx];
  __syncthreads();
  float acc[8][2];
#pragma unroll
  for (int r = 0; r < 8; ++r) { acc[r][0] = 0.f; acc[r][1] = 0.f; }
#pragma unroll 4
  for (int d = 0; d < DD; ++d) {
    const float2 w = ((const float2*)(Wm1 + (size_t)d * HH))[tid];
#pragma unroll
    for (int r = 0; r < 8; ++r) {
      const float a = vrow[r * DD + d];
      acc[r][0] += a * w.x; acc[r][1] += a * w.y;
    }
  }
  const float2 b = ((const float2*)bm1)[tid];
  const float2 m = ((const float2*)wm2)[tid];
  const float sc = bm2[0];
  for (int r = 0; r < 8; ++r) {
    float p = fmaxf(acc[r][0] + b.x, 0.f) * m.x + fmaxf(acc[r][1] + b.y, 0.f) * m.y;
    p = waveSum(p);
    if ((tid & 63) == 0) red[tid >> 6] = p;
    __syncthreads();
    if (tid == 0) {
      float t = red[0];
#pragma unroll
      for (int w8 = 1; w8 < 8; ++w8) t += red[w8];
      scores[base + r] = t + sc;
    }
    __syncthreads();
  }
}

// ---------------- K2: bitonic sort (score desc, idx asc) -> top 400 ----------------
__global__ __launch_bounds__(1024) void topsort_kernel(
    const float* __restrict__ scores, int* __restrict__ top) {
  __shared__ float ks[2048];
  __shared__ int   ki[2048];
  const int tid = threadIdx.x;
  for (int e = tid; e < 2048; e += 1024) {
    ks[e] = (e < NVEC) ? scores[e] : -INFINITY;
    ki[e] = e;
  }
  __syncthreads();
  for (int k = 2; k <= 2048; k <<= 1) {
    for (int j = k >> 1; j > 0; j >>= 1) {
      for (int e = tid; e < 2048; e += 1024) {
        const int l = e ^ j;
        if (l > e) {
          const float s1 = ks[e], s2 = ks[l];
          const int i1 = ki[e], i2 = ki[l];
          const bool first = (s1 > s2) || (s1 == s2 && i1 < i2);
          const bool up = ((e & k) == 0);
          if (up ? !first : first) {
            ks[e] = s2; ks[l] = s1; ki[e] = i2; ki[l] = i1;
          }
        }
      }
      __syncthreads();
    }
  }
  if (tid < MSEL) top[tid] = ki[tid];
}

// ---------------- K3: lexsort by (start,end,pos) asc, reversed ----------------
__global__ __launch_bounds__(256) void lexsort_kernel(
    const int* __restrict__ top, const int* __restrict__ sst,
    const int* __restrict__ sen, const float* __restrict__ scores,
    int* __restrict__ perm, float* __restrict__ sfin) {
  __shared__ int s_st[512], s_en[512], s_j[512];
  const int tid = threadIdx.x;
  for (int e = tid; e < 512; e += 256) {
    if (e < MSEL) { const int ti = top[e]; s_st[e] = sst[ti]; s_en[e] = sen[ti]; }
    else { s_st[e] = 0x7fffffff; s_en[e] = 0x7fffffff; }
    s_j[e] = e;
  }
  __syncthreads();
  for (int k = 2; k <= 512; k <<= 1) {
    for (int j = k >> 1; j > 0; j >>= 1) {
      for (int e = tid; e < 512; e += 256) {
        const int l = e ^ j;
        if (l > e) {
          const int a0 = s_st[e], a1 = s_en[e], a2 = s_j[e];
          const int b0 = s_st[l], b1 = s_en[l], b2 = s_j[l];
          const bool first = (a0 < b0) || (a0 == b0 && (a1 < b1 || (a1 == b1 && a2 < b2)));
          const bool up = ((e & k) == 0);
          if (up ? !first : first) {
            s_st[e] = b0; s_en[e] = b1; s_j[e] = b2;
            s_st[l] = a0; s_en[l] = a1; s_j[l] = a2;
          }
        }
      }
      __syncthreads();
    }
  }
  for (int i = tid; i < MSEL; i += 256) {
    const int src = s_j[MSEL - 1 - i];
    const int vi = top[src];
    perm[i] = vi;
    sfin[i] = scores[vi];
  }
}

// ---------------- K4: Ha = v@Wa, Hv = v@Wb; gather Vp (f32) + Vpb (bf16) ----------------
__global__ __launch_bounds__(256) void hab_kernel(
    const float* __restrict__ vectors, const float* __restrict__ Wp1,
    const int* __restrict__ perm, float* __restrict__ Ha, float* __restrict__ Hv,
    float* __restrict__ Vp, ushort* __restrict__ Vpb) {
  __shared__ float vrow[8 * DD];
  const int tid = threadIdx.x;
  const int base = blockIdx.x * 8;
  const int mat = blockIdx.y >> 1;       // 0 = Wa, 1 = Wb
  const int half = blockIdx.y & 1;       // col half
  for (int r = 0; r < 8; ++r) {
    const int pi = perm[base + r];
    for (int d = tid; d < DD; d += 256) {
      const float val = vectors[pi * DD + d];
      vrow[r * DD + d] = val;
      if (blockIdx.y == 0) {
        Vp[(size_t)(base + r) * DD + d] = val;
        Vpb[(size_t)(base + r) * DD + d] = (ushort)f2bf(val);
      }
    }
  }
  __syncthreads();
  float acc[8][2];
#pragma unroll
  for (int r = 0; r < 8; ++r) { acc[r][0] = 0.f; acc[r][1] = 0.f; }
  const float* W = Wp1 + (size_t)mat * DD * HH + half * 512;
#pragma unroll 4
  for (int d = 0; d < DD; ++d) {
    const float2 w = ((const float2*)(W + (size_t)d * HH))[tid];
#pragma unroll
    for (int r = 0; r < 8; ++r) {
      const float a = vrow[r * DD + d];
      acc[r][0] += a * w.x; acc[r][1] += a * w.y;
    }
  }
  float* dst = mat ? Hv : Ha;
  for (int r = 0; r < 8; ++r) {
    const int row = base + r;
    if (mat == 0 && row >= MR) continue;
    ((float2*)(dst + (size_t)row * HH + half * 512))[tid] =
        make_float2(acc[r][0], acc[r][1]);
  }
}

// ---------------- K4b: Wt[n][k] = bf16(Wab[k][n]) (transpose + cast, once) ----------------
__global__ __launch_bounds__(256) void wt_kernel(
    const float* __restrict__ Wp1, ushort* __restrict__ Wt) {
  __shared__ float tile[64][65];
  const int kb = blockIdx.x;   // 12 tiles over K=768
  const int nb = blockIdx.y;   // 16 tiles over N=1024
  const float* Wab = Wp1 + 2 * DD * HH;
  for (int idx = threadIdx.x; idx < 64 * 64; idx += 256) {
    const int kk = idx >> 6, nn = idx & 63;
    tile[kk][nn] = Wab[(size_t)(kb * 64 + kk) * HH + nb * 64 + nn];
  }
  __syncthreads();
  for (int idx = threadIdx.x; idx < 64 * 64; idx += 256) {
    const int nn = idx >> 6, kk = idx & 63;
    Wt[(size_t)(nb * 64 + nn) * DD + kb * 64 + kk] = (ushort)f2bf(tile[kk][nn]);
  }
}

// ---------------- K5: pairwise einsum GEMM, 128x256 tile, 8 waves, 16 waves/CU ----------------
// Wave tile stays 64x64 (acc[4][4] = 64 AGPR -> total ~128 regs -> 16 waves/CU),
// but per-thread staging halves (A: 2 chunks, was 4) and A-product redundancy
// drops 8x -> 4x (NNB 4). 2 blocks/CU x 8 waves; cross-block overlap retained.
__global__ __launch_bounds__(512, 2) void pair_kernel(
    const float* __restrict__ Vp, const ushort* __restrict__ Vpb,
    const ushort* __restrict__ Wt,
    const float* __restrict__ bp1, const float* __restrict__ wp2,
    const float* __restrict__ Ha, const float* __restrict__ Hv,
    float* __restrict__ pp) {
  __shared__ __align__(16) ushort As[BM * BK];      // 16 KB
  __shared__ __align__(16) ushort Bs[BN * BK];      // 32 KB
  __shared__ float redp[BM][4];                     // 2 KB
  const int tid = threadIdx.x;
  const int mb = blockIdx.x;          // 0..797  (i*2 + khalf)
  const int nb = blockIdx.y;          // 0..3
  const int i = mb >> 1;
  const int khalf = mb & 1;
  const int n0 = nb * BN;
  const int lane = tid & 63;
  const int wid = tid >> 6;           // 0..7
  const int wr = wid >> 2, wc = wid & 3;
  const int lhi = lane >> 4, llo = lane & 15;

  // ---- stage geometry ----
  // A: 128 rows x 8 chunks = 1024 chunks -> 2/thread; B: 2048 chunks -> 4/thread.
  const int cs = tid & 7;
  const int rb9 = tid >> 3;                   // 0..63
  const int csx = cs ^ (rb9 & 7);             // same for both A chunks
  const ushort* vsrc[2];
  int rowA[2];
#pragma unroll
  for (int it = 0; it < 2; ++it) {
    rowA[it] = it * 64 + rb9;                 // 0..127
    int j = i + 1 + khalf * BM + rowA[it];
    if (j > MR) j = MR;
    vsrc[it] = Vpb + (size_t)j * DD + cs * 8;
  }
  int rowB[4];
#pragma unroll
  for (int it = 0; it < 4; ++it) rowB[it] = it * 64 + rb9;   // 0..255
  const float* avp = Vp + (size_t)i * DD + cs * 8;   // L1-hot row i

  f32x4 acc[4][4];
#pragma unroll
  for (int a = 0; a < 4; ++a)
#pragma unroll
    for (int b = 0; b < 4; ++b) acc[a][b] = (f32x4){0.f, 0.f, 0.f, 0.f};

  for (int kt = 0; kt < NKT; ++kt) {
    const int kg = kt * BK;
    // ---- stage phase: A-src loads FIRST (oldest VMEM), then B-DMAs, then prodcvt ----
    bf16x8 bv[2];
    float av[8];
#pragma unroll
    for (int it = 0; it < 2; ++it) bv[it] = *(const bf16x8*)(vsrc[it] + kg);
    *(float4*)(av) = *(const float4*)(avp + kg);
    *(float4*)(av + 4) = *(const float4*)(avp + kg + 4);
#pragma unroll
    for (int it = 0; it < 4; ++it)
      gload_lds16(Wt + (size_t)(n0 + rowB[it]) * DD + kg + csx * 8,
                  (char*)Bs + (it * 512 + tid) * 16);
#pragma unroll
    for (int it = 0; it < 2; ++it)
      *(bf16x8*)((char*)As + rowA[it] * 128 + (csx << 4)) = prodcvt(av, bv[it]);
    __syncthreads();   // drains DMA writes + A ds_writes
    // ---- compute phase: 2 k-steps of 32; 4x4 fragments per wave ----
#pragma unroll
    for (int ks = 0; ks < 2; ++ks) {
      bf16x8 af[4], bfr[4];
#pragma unroll
      for (int mi = 0; mi < 4; ++mi) {
        const int row = wr * 64 + mi * 16 + llo;
        const int ch = (ks * 4 + lhi) ^ (row & 7);
        af[mi] = *(const bf16x8*)((const char*)As + row * 128 + (ch << 4));
      }
#pragma unroll
      for (int ni = 0; ni < 4; ++ni) {
        const int row = wc * 64 + ni * 16 + llo;
        const int ch = (ks * 4 + lhi) ^ (row & 7);
        bfr[ni] = *(const bf16x8*)((const char*)Bs + row * 128 + (ch << 4));
      }
#pragma unroll
      for (int mi = 0; mi < 4; ++mi)
#pragma unroll
        for (int ni = 0; ni < 4; ++ni)
          acc[mi][ni] = __builtin_amdgcn_mfma_f32_16x16x32_bf16(af[mi], bfr[ni], acc[mi][ni], 0, 0, 0);
    }
    __syncthreads();   // all reads done before next stage overwrites
  }

  // ---- epilogue: relu(acc + Ha_i + Hv_j + bp1) . wp2 over this wave's 64 cols ----
  float hb4[4], wpv[4];
  int cg[4];
#pragma unroll
  for (int ni = 0; ni < 4; ++ni) {
    const int col = n0 + wc * 64 + ni * 16 + llo;
    cg[ni] = col;
    hb4[ni] = Ha[(size_t)i * HH + col] + bp1[col];
    wpv[ni] = wp2[col];
  }
#pragma unroll
  for (int mi = 0; mi < 4; ++mi) {
#pragma unroll
    for (int r = 0; r < 4; ++r) {
      const int rowl = wr * 64 + mi * 16 + lhi * 4 + r;
      int j = i + 1 + khalf * BM + rowl;
      if (j > MR) j = MR;
      float part = 0.f;
#pragma unroll
      for (int ni = 0; ni < 4; ++ni) {
        const float pre = acc[mi][ni][r] + hb4[ni] + Hv[(size_t)j * HH + cg[ni]];
        part += fmaxf(pre, 0.f) * wpv[ni];
      }
      part += __shfl_xor(part, 1, 64);
      part += __shfl_xor(part, 2, 64);
      part += __shfl_xor(part, 4, 64);
      part += __shfl_xor(part, 8, 64);
      if (llo == 0) redp[rowl][wc] = part;   // per-wave column-quarter partial
    }
  }
  __syncthreads();
  if (tid < BM)
    pp[(size_t)nb * NPAIR + (size_t)i * PPAD + khalf * BM + tid] =
        redp[tid][0] + redp[tid][1] + redp[tid][2] + redp[tid][3];
}

// ---------------- K6: sum partials + bias + scores, mask, softmax over 251 ----------------
__global__ __launch_bounds__(256) void softmax_kernel(
    const float* __restrict__ pp, const float* __restrict__ sfin,
    const float* __restrict__ bp2, float* __restrict__ out) {
  __shared__ float red[4];
  const int i = blockIdx.x, tid = threadIdx.x;
  float v;
  if (tid < KNUM) {
    const int jidx = i + 1 + tid;
    const bool valid = jidx < MSEL;
    const int jc = valid ? jidx : MR;
    float s = 0.f;
#pragma unroll
    for (int b = 0; b < NNB; ++b) s += pp[(size_t)b * NPAIR + i * PPAD + tid];
    v = valid ? (s + bp2[0] + sfin[jc] + sfin[i]) : -INFINITY;
  } else if (tid == KNUM) v = 0.f;
  else v = -INFINITY;
  float mx = waveMax(v);
  if ((tid & 63) == 0) red[tid >> 6] = mx;
  __syncthreads();
  const float m = fmaxf(fmaxf(red[0], red[1]), fmaxf(red[2], red[3]));
  __syncthreads();
  const float e = (tid <= KNUM) ? expf(v - m) : 0.f;
  float s = waveSum(e);
  if ((tid & 63) == 0) red[tid >> 6] = s;
  __syncthreads();
  const float tot = red[0] + red[1] + red[2] + red[3];
  if (tid <= KNUM) out[i * OUTW + tid] = e / tot;
}

extern "C" void kernel_launch(void* const* d_in, const int* in_sizes, int n_in,
                              void* d_out, int out_size, void* d_ws, size_t ws_size,
                              hipStream_t stream) {
  const float* vectors = (const float*)d_in[0];
  const float* Wm1 = (const float*)d_in[1];
  const float* bm1 = (const float*)d_in[2];
  const float* wm2 = (const float*)d_in[3];
  const float* bm2 = (const float*)d_in[4];
  const float* Wp1 = (const float*)d_in[5];
  const float* bp1 = (const float*)d_in[6];
  const float* wp2 = (const float*)d_in[7];
  const float* bp2 = (const float*)d_in[8];
  const int* sst = (const int*)d_in[9];
  const int* sen = (const int*)d_in[10];
  float* out = (float*)d_out;
  char* ws = (char*)d_ws;

  float* scores = (float*)(ws);                          // 2000 f32
  int*   top    = (int*)(ws + 8192);                     // 400 i32
  int*   perm   = (int*)(ws + 10240);                    // 400 i32
  float* sfin   = (float*)(ws + 12288);                  // 400 f32
  float* Ha     = (float*)(ws + 16384);                  // 400*1024 f32
  float* Hv     = (float*)(ws + 16384 + 1638400);        // 400*1024 f32
  float* Vp     = (float*)(ws + 3293184);                // 400*768 f32
  ushort* Wt    = (ushort*)(ws + 4521984);               // 1024*768 bf16
  ushort* Vpb   = (ushort*)(ws + 6094848);               // 400*768 bf16
  float* pp     = (float*)(ws + 6709248);                // 4 * 102144 f32 partials

  scores_kernel<<<NVEC / 8, 512, 0, stream>>>(vectors, Wm1, bm1, wm2, bm2, scores);
  topsort_kernel<<<1, 1024, 0, stream>>>(scores, top);
  lexsort_kernel<<<1, 256, 0, stream>>>(top, sst, sen, scores, perm, sfin);
  wt_kernel<<<dim3(12, 16), 256, 0, stream>>>(Wp1, Wt);
  hab_kernel<<<dim3(MSEL / 8, 4), 256, 0, stream>>>(vectors, Wp1, perm, Ha, Hv, Vp, Vpb);
  pair_kernel<<<dim3(MR * 2, NNB), 512, 0, stream>>>(Vp, Vpb, Wt, bp1, wp2, Ha, Hv, pp);
  softmax_kernel<<<MR, 256, 0, stream>>>(pp, sfin, bp2, out);
}

// Round 16
// 400.800 us; speedup vs baseline: 1.2074x; 1.0117x over previous
//
#include <hip/hip_runtime.h>
#include <hip/hip_bf16.h>
#include <math.h>

#define NVEC 2000
#define DD   768
#define HH   1024
#define KNUM 250
#define MSEL 400
#define MR   399     // m-1 rows
#define OUTW 251
#define PPAD 256                 // padded antecedents per anaphor
#define NPAIR (MR * PPAD)        // 102144 padded pair rows
#define BM 128
#define BN 256
#define BK 64
#define NKT (DD / BK)            // 12
#define NNB (HH / BN)            // 4
#define NKQ (DD / 32)            // 24 fragment k-tiles

typedef short  bf16x8 __attribute__((ext_vector_type(8)));
typedef float  f32x4  __attribute__((ext_vector_type(4)));
typedef unsigned int u32;
typedef u32    u32x4  __attribute__((ext_vector_type(4)));

__device__ __forceinline__ float waveSum(float p) {
#pragma unroll
  for (int off = 32; off >= 1; off >>= 1) p += __shfl_xor(p, off, 64);
  return p;
}
__device__ __forceinline__ float waveMax(float p) {
#pragma unroll
  for (int off = 32; off >= 1; off >>= 1) p = fmaxf(p, __shfl_xor(p, off, 64));
  return p;
}
__device__ __forceinline__ short f2bf(float f) {
  __hip_bfloat16 h = __float2bfloat16(f);     // RNE; pairs fuse to v_cvt_pk_bf16_f32
  return __builtin_bit_cast(short, h);
}
// x[e] = bf16( av[e] * f32(b[e]) )  -- 8-element chunk, in registers
__device__ __forceinline__ bf16x8 prodcvt(const float* av, bf16x8 b) {
  u32x4 u = __builtin_bit_cast(u32x4, b);
  bf16x8 r;
#pragma unroll
  for (int p = 0; p < 4; ++p) {
    const float blo = __builtin_bit_cast(float, u[p] << 16);
    const float bhi = __builtin_bit_cast(float, u[p] & 0xffff0000u);
    r[2 * p]     = f2bf(av[2 * p]     * blo);
    r[2 * p + 1] = f2bf(av[2 * p + 1] * bhi);
  }
  return r;
}

// ---------------- K1: scores = relu(V @ Wm1 + bm1) @ wm2 + bm2 ----------------
__global__ __launch_bounds__(512) void scores_kernel(
    const float* __restrict__ vectors, const float* __restrict__ Wm1,
    const float* __restrict__ bm1, const float* __restrict__ wm2,
    const float* __restrict__ bm2, float* __restrict__ scores) {
  __shared__ float vrow[8 * DD];
  __shared__ float red[8];
  const int tid = threadIdx.x;
  const int base = blockIdx.x * 8;
  for (int idx = tid; idx < 8 * DD; idx += 512)
    vrow[idx] = vectors[base * DD + idx];
  __syncthreads();
  float acc[8][2];
#pragma unroll
  for (int r = 0; r < 8; ++r) { acc[r][0] = 0.f; acc[r][1] = 0.f; }
#pragma unroll 4
  for (int d = 0; d < DD; ++d) {
    const float2 w = ((const float2*)(Wm1 + (size_t)d * HH))[tid];
#pragma unroll
    for (int r = 0; r < 8; ++r) {
      const float a = vrow[r * DD + d];
      acc[r][0] += a * w.x; acc[r][1] += a * w.y;
    }
  }
  const float2 b = ((const float2*)bm1)[tid];
  const float2 m = ((const float2*)wm2)[tid];
  const float sc = bm2[0];
  for (int r = 0; r < 8; ++r) {
    float p = fmaxf(acc[r][0] + b.x, 0.f) * m.x + fmaxf(acc[r][1] + b.y, 0.f) * m.y;
    p = waveSum(p);
    if ((tid & 63) == 0) red[tid >> 6] = p;
    __syncthreads();
    if (tid == 0) {
      float t = red[0];
#pragma unroll
      for (int w8 = 1; w8 < 8; ++w8) t += red[w8];
      scores[base + r] = t + sc;
    }
    __syncthreads();
  }
}

// ---------------- K2: merged top-400 bitonic sort + lexsort (1 block) ----------------
__global__ __launch_bounds__(1024) void sort_kernel(
    const float* __restrict__ scores, const int* __restrict__ sst,
    const int* __restrict__ sen, int* __restrict__ perm,
    float* __restrict__ sfin) {
  __shared__ float ks[2048];
  __shared__ int   ki[2048];
  __shared__ int s_st[512], s_en[512], s_j[512];
  const int tid = threadIdx.x;
  // --- phase 1: bitonic sort of (score desc, idx asc), 2048 elems ---
  for (int e = tid; e < 2048; e += 1024) {
    ks[e] = (e < NVEC) ? scores[e] : -INFINITY;
    ki[e] = e;
  }
  __syncthreads();
  for (int k = 2; k <= 2048; k <<= 1) {
    for (int j = k >> 1; j > 0; j >>= 1) {
      for (int e = tid; e < 2048; e += 1024) {
        const int l = e ^ j;
        if (l > e) {
          const float s1 = ks[e], s2 = ks[l];
          const int i1 = ki[e], i2 = ki[l];
          const bool first = (s1 > s2) || (s1 == s2 && i1 < i2);
          const bool up = ((e & k) == 0);
          if (up ? !first : first) {
            ks[e] = s2; ks[l] = s1; ki[e] = i2; ki[l] = i1;
          }
        }
      }
      __syncthreads();
    }
  }
  // ki[0..MSEL) = top indices
  // --- phase 2: lexsort by (start,end,pos) asc over the top 400 ---
  for (int e = tid; e < 512; e += 1024) {
    if (e < MSEL) { const int ti = ki[e]; s_st[e] = sst[ti]; s_en[e] = sen[ti]; }
    else { s_st[e] = 0x7fffffff; s_en[e] = 0x7fffffff; }
    s_j[e] = e;
  }
  __syncthreads();
  for (int k = 2; k <= 512; k <<= 1) {
    for (int j = k >> 1; j > 0; j >>= 1) {
      for (int e = tid; e < 512; e += 1024) {
        const int l = e ^ j;
        if (l > e) {
          const int a0 = s_st[e], a1 = s_en[e], a2 = s_j[e];
          const int b0 = s_st[l], b1 = s_en[l], b2 = s_j[l];
          const bool first = (a0 < b0) || (a0 == b0 && (a1 < b1 || (a1 == b1 && a2 < b2)));
          const bool up = ((e & k) == 0);
          if (up ? !first : first) {
            s_st[e] = b0; s_en[e] = b1; s_j[e] = b2;
            s_st[l] = a0; s_en[l] = a1; s_j[l] = a2;
          }
        }
      }
      __syncthreads();
    }
  }
  for (int i = tid; i < MSEL; i += 1024) {
    const int src = s_j[MSEL - 1 - i];    // reversal of ascending lexsort
    const int vi = ki[src];
    perm[i] = vi;
    sfin[i] = scores[vi];
  }
}

// ---------------- K4: Ha = v@Wa, Hv = v@Wb; gather Vp (f32) + Vpb (bf16) ----------------
__global__ __launch_bounds__(256) void hab_kernel(
    const float* __restrict__ vectors, const float* __restrict__ Wp1,
    const int* __restrict__ perm, float* __restrict__ Ha, float* __restrict__ Hv,
    float* __restrict__ Vp, ushort* __restrict__ Vpb) {
  __shared__ float vrow[8 * DD];
  const int tid = threadIdx.x;
  const int base = blockIdx.x * 8;
  const int mat = blockIdx.y >> 1;       // 0 = Wa, 1 = Wb
  const int half = blockIdx.y & 1;       // col half
  for (int r = 0; r < 8; ++r) {
    const int pi = perm[base + r];
    for (int d = tid; d < DD; d += 256) {
      const float val = vectors[pi * DD + d];
      vrow[r * DD + d] = val;
      if (blockIdx.y == 0) {
        Vp[(size_t)(base + r) * DD + d] = val;
        Vpb[(size_t)(base + r) * DD + d] = (ushort)f2bf(val);
      }
    }
  }
  __syncthreads();
  float acc[8][2];
#pragma unroll
  for (int r = 0; r < 8; ++r) { acc[r][0] = 0.f; acc[r][1] = 0.f; }
  const float* W = Wp1 + (size_t)mat * DD * HH + half * 512;
#pragma unroll 4
  for (int d = 0; d < DD; ++d) {
    const float2 w = ((const float2*)(W + (size_t)d * HH))[tid];
#pragma unroll
    for (int r = 0; r < 8; ++r) {
      const float a = vrow[r * DD + d];
      acc[r][0] += a * w.x; acc[r][1] += a * w.y;
    }
  }
  float* dst = mat ? Hv : Ha;
  for (int r = 0; r < 8; ++r) {
    const int row = base + r;
    if (mat == 0 && row >= MR) continue;
    ((float2*)(dst + (size_t)row * HH + half * 512))[tid] =
        make_float2(acc[r][0], acc[r][1]);
  }
}

// ---------------- K4b: Wt2 = Wab transposed+cast, packed in MFMA-fragment order ----------------
// Fragment (nt, kq): 16 cols x 32 k. Lane (llo,lhi) owns col=nt*16+llo, k=kq*32+lhi*8..+8.
// Storage: Wt2[((nt*NKQ + kq)*64 + lane)*8 + e] -> a wave's B-frag load = contiguous 1 KB.
__global__ __launch_bounds__(256) void wt2_kernel(
    const float* __restrict__ Wp1, ushort* __restrict__ Wt2) {
  __shared__ float tile[64][65];
  const int kb = blockIdx.x;   // 12 tiles over K=768
  const int nb = blockIdx.y;   // 16 tiles over N=1024
  const float* Wab = Wp1 + 2 * DD * HH;
  for (int idx = threadIdx.x; idx < 64 * 64; idx += 256) {
    const int kk = idx >> 6, nn = idx & 63;
    tile[kk][nn] = Wab[(size_t)(kb * 64 + kk) * HH + nb * 64 + nn];
  }
  __syncthreads();
  for (int c = threadIdx.x; c < 512; c += 256) {   // 512 16B-chunks per 64x64 tile
    const int lane = c & 63;
    const int sub = c >> 6;          // ntl*2 + kql
    const int ntl = sub >> 1, kql = sub & 1;
    const int llo = lane & 15, lhi = lane >> 4;
    const int nt = nb * 4 + ntl;
    const int kq = kb * 2 + kql;
    bf16x8 v;
#pragma unroll
    for (int e = 0; e < 8; ++e)
      v[e] = f2bf(tile[kql * 32 + lhi * 8 + e][ntl * 16 + llo]);
    *(bf16x8*)(Wt2 + ((size_t)(nt * NKQ + kq) * 64 + lane) * 8) = v;
  }
}

// ---------------- K5: pairwise einsum GEMM; B direct-from-global (fragment-packed) ----------------
// 128x256 tile, 8 waves 2Mx4N, wave tile 64x64 (acc[4][4] = 64 AGPR). A staged in LDS
// (products computed once, XOR-swizzled); B-frags load straight from L2-resident Wt2
// as fully-coalesced 1KB wave loads -> Bs LDS and its DMA removed. LDS 18.25 KB,
// 16 waves/CU (2 blocks x 8 waves) retained.
__global__ __launch_bounds__(512, 2) void pair_kernel(
    const float* __restrict__ Vp, const ushort* __restrict__ Vpb,
    const ushort* __restrict__ Wt2,
    const float* __restrict__ bp1, const float* __restrict__ wp2,
    const float* __restrict__ Ha, const float* __restrict__ Hv,
    float* __restrict__ pp) {
  __shared__ __align__(16) ushort As[BM * BK];      // 16 KB
  __shared__ float redp[BM][4];                     // 2 KB
  const int tid = threadIdx.x;
  const int mb = blockIdx.x;          // 0..797  (i*2 + khalf)
  const int nb = blockIdx.y;          // 0..3
  const int i = mb >> 1;
  const int khalf = mb & 1;
  const int n0 = nb * BN;
  const int lane = tid & 63;
  const int wid = tid >> 6;           // 0..7
  const int wr = wid >> 2, wc = wid & 3;
  const int lhi = lane >> 4, llo = lane & 15;

  // ---- stage geometry (A): 2 chunks/thread ----
  const int cs = tid & 7;
  const int rb9 = tid >> 3;                   // 0..63
  const int csx = cs ^ (rb9 & 7);             // same for both A chunks
  const ushort* vsrc[2];
  int rowA[2];
#pragma unroll
  for (int it = 0; it < 2; ++it) {
    rowA[it] = it * 64 + rb9;                 // 0..127
    int j = i + 1 + khalf * BM + rowA[it];
    if (j > MR) j = MR;
    vsrc[it] = Vpb + (size_t)j * DD + cs * 8;
  }
  const float* avp = Vp + (size_t)i * DD + cs * 8;   // L1-hot row i

  // ---- B fragment base: wave's (wc, ni, kq) frag = 1KB at base + (ni*NKQ+kq)*512 ----
  const ushort* wt2base = Wt2 + ((size_t)((n0 >> 4) + wc * 4) * NKQ) * 512 + lane * 8;

  f32x4 acc[4][4];
#pragma unroll
  for (int a = 0; a < 4; ++a)
#pragma unroll
    for (int b = 0; b < 4; ++b) acc[a][b] = (f32x4){0.f, 0.f, 0.f, 0.f};

  for (int kt = 0; kt < NKT; ++kt) {
    const int kg = kt * BK;
    // ---- stage phase: A-src loads, products -> LDS ----
    bf16x8 bv[2];
    float av[8];
#pragma unroll
    for (int it = 0; it < 2; ++it) bv[it] = *(const bf16x8*)(vsrc[it] + kg);
    *(float4*)(av) = *(const float4*)(avp + kg);
    *(float4*)(av + 4) = *(const float4*)(avp + kg + 4);
#pragma unroll
    for (int it = 0; it < 2; ++it)
      *(bf16x8*)((char*)As + rowA[it] * 128 + (csx << 4)) = prodcvt(av, bv[it]);
    __syncthreads();   // A tile visible
    // ---- compute phase: B-frag global loads (coalesced 1KB) + af ds_reads + MFMA ----
    bf16x8 bfr0[4], bfr1[4];
#pragma unroll
    for (int ni = 0; ni < 4; ++ni)
      bfr0[ni] = *(const bf16x8*)(wt2base + (ni * NKQ + kt * 2 + 0) * 512);
#pragma unroll
    for (int ni = 0; ni < 4; ++ni)
      bfr1[ni] = *(const bf16x8*)(wt2base + (ni * NKQ + kt * 2 + 1) * 512);
    bf16x8 af[4];
#pragma unroll
    for (int mi = 0; mi < 4; ++mi) {
      const int row = wr * 64 + mi * 16 + llo;
      const int ch = lhi ^ (row & 7);
      af[mi] = *(const bf16x8*)((const char*)As + row * 128 + (ch << 4));
    }
#pragma unroll
    for (int mi = 0; mi < 4; ++mi)
#pragma unroll
      for (int ni = 0; ni < 4; ++ni)
        acc[mi][ni] = __builtin_amdgcn_mfma_f32_16x16x32_bf16(af[mi], bfr0[ni], acc[mi][ni], 0, 0, 0);
#pragma unroll
    for (int mi = 0; mi < 4; ++mi) {
      const int row = wr * 64 + mi * 16 + llo;
      const int ch = (4 + lhi) ^ (row & 7);
      af[mi] = *(const bf16x8*)((const char*)As + row * 128 + (ch << 4));
    }
#pragma unroll
    for (int mi = 0; mi < 4; ++mi)
#pragma unroll
      for (int ni = 0; ni < 4; ++ni)
        acc[mi][ni] = __builtin_amdgcn_mfma_f32_16x16x32_bf16(af[mi], bfr1[ni], acc[mi][ni], 0, 0, 0);
    __syncthreads();   // all As reads done before next stage overwrites
  }

  // ---- epilogue: relu(acc + Ha_i + Hv_j + bp1) . wp2 over this wave's 64 cols ----
  float hb4[4], wpv[4];
  int cg[4];
#pragma unroll
  for (int ni = 0; ni < 4; ++ni) {
    const int col = n0 + wc * 64 + ni * 16 + llo;
    cg[ni] = col;
    hb4[ni] = Ha[(size_t)i * HH + col] + bp1[col];
    wpv[ni] = wp2[col];
  }
#pragma unroll
  for (int mi = 0; mi < 4; ++mi) {
#pragma unroll
    for (int r = 0; r < 4; ++r) {
      const int rowl = wr * 64 + mi * 16 + lhi * 4 + r;
      int j = i + 1 + khalf * BM + rowl;
      if (j > MR) j = MR;
      float part = 0.f;
#pragma unroll
      for (int ni = 0; ni < 4; ++ni) {
        const float pre = acc[mi][ni][r] + hb4[ni] + Hv[(size_t)j * HH + cg[ni]];
        part += fmaxf(pre, 0.f) * wpv[ni];
      }
      part += __shfl_xor(part, 1, 64);
      part += __shfl_xor(part, 2, 64);
      part += __shfl_xor(part, 4, 64);
      part += __shfl_xor(part, 8, 64);
      if (llo == 0) redp[rowl][wc] = part;   // per-wave column-quarter partial
    }
  }
  __syncthreads();
  if (tid < BM)
    pp[(size_t)nb * NPAIR + (size_t)i * PPAD + khalf * BM + tid] =
        redp[tid][0] + redp[tid][1] + redp[tid][2] + redp[tid][3];
}

// ---------------- K6: sum partials + bias + scores, mask, softmax over 251 ----------------
__global__ __launch_bounds__(256) void softmax_kernel(
    const float* __restrict__ pp, const float* __restrict__ sfin,
    const float* __restrict__ bp2, float* __restrict__ out) {
  __shared__ float red[4];
  const int i = blockIdx.x, tid = threadIdx.x;
  float v;
  if (tid < KNUM) {
    const int jidx = i + 1 + tid;
    const bool valid = jidx < MSEL;
    const int jc = valid ? jidx : MR;
    float s = 0.f;
#pragma unroll
    for (int b = 0; b < NNB; ++b) s += pp[(size_t)b * NPAIR + i * PPAD + tid];
    v = valid ? (s + bp2[0] + sfin[jc] + sfin[i]) : -INFINITY;
  } else if (tid == KNUM) v = 0.f;
  else v = -INFINITY;
  float mx = waveMax(v);
  if ((tid & 63) == 0) red[tid >> 6] = mx;
  __syncthreads();
  const float m = fmaxf(fmaxf(red[0], red[1]), fmaxf(red[2], red[3]));
  __syncthreads();
  const float e = (tid <= KNUM) ? expf(v - m) : 0.f;
  float s = waveSum(e);
  if ((tid & 63) == 0) red[tid >> 6] = s;
  __syncthreads();
  const float tot = red[0] + red[1] + red[2] + red[3];
  if (tid <= KNUM) out[i * OUTW + tid] = e / tot;
}

extern "C" void kernel_launch(void* const* d_in, const int* in_sizes, int n_in,
                              void* d_out, int out_size, void* d_ws, size_t ws_size,
                              hipStream_t stream) {
  const float* vectors = (const float*)d_in[0];
  const float* Wm1 = (const float*)d_in[1];
  const float* bm1 = (const float*)d_in[2];
  const float* wm2 = (const float*)d_in[3];
  const float* bm2 = (const float*)d_in[4];
  const float* Wp1 = (const float*)d_in[5];
  const float* bp1 = (const float*)d_in[6];
  const float* wp2 = (const float*)d_in[7];
  const float* bp2 = (const float*)d_in[8];
  const int* sst = (const int*)d_in[9];
  const int* sen = (const int*)d_in[10];
  float* out = (float*)d_out;
  char* ws = (char*)d_ws;

  float* scores = (float*)(ws);                          // 2000 f32
  int*   perm   = (int*)(ws + 10240);                    // 400 i32
  float* sfin   = (float*)(ws + 12288);                  // 400 f32
  float* Ha     = (float*)(ws + 16384);                  // 400*1024 f32
  float* Hv     = (float*)(ws + 16384 + 1638400);        // 400*1024 f32
  float* Vp     = (float*)(ws + 3293184);                // 400*768 f32
  ushort* Wt2   = (ushort*)(ws + 4521984);               // 1024*768 bf16 (fragment order)
  ushort* Vpb   = (ushort*)(ws + 6094848);               // 400*768 bf16
  float* pp     = (float*)(ws + 6709248);                // 4 * 102144 f32 partials

  scores_kernel<<<NVEC / 8, 512, 0, stream>>>(vectors, Wm1, bm1, wm2, bm2, scores);
  sort_kernel<<<1, 1024, 0, stream>>>(scores, sst, sen, perm, sfin);
  wt2_kernel<<<dim3(12, 16), 256, 0, stream>>>(Wp1, Wt2);
  hab_kernel<<<dim3(MSEL / 8, 4), 256, 0, stream>>>(vectors, Wp1, perm, Ha, Hv, Vp, Vpb);
  pair_kernel<<<dim3(MR * 2, NNB), 512, 0, stream>>>(Vp, Vpb, Wt2, bp1, wp2, Ha, Hv, pp);
  softmax_kernel<<<MR, 256, 0, stream>>>(pp, sfin, bp2, out);
}

// Round 17
// 388.451 us; speedup vs baseline: 1.2458x; 1.0318x over previous
//
#include <hip/hip_runtime.h>
#include <hip/hip_bf16.h>
#include <math.h>

#define NVEC 2000
#define DD   768
#define HH   1024
#define KNUM 250
#define MSEL 400
#define MR   399     // m-1 rows
#define OUTW 251
#define PPAD 256                 // padded antecedents per anaphor
#define NPAIR (MR * PPAD)        // 102144 padded pair rows
#define BM 128
#define BN 256
#define BK 64
#define NKT (DD / BK)            // 12
#define NNB (HH / BN)            // 4
#define SCOREBLKS (NVEC / 8)     // 250

typedef short  bf16x8 __attribute__((ext_vector_type(8)));
typedef float  f32x4  __attribute__((ext_vector_type(4)));
typedef unsigned int u32;
typedef u32    u32x4  __attribute__((ext_vector_type(4)));

__device__ __forceinline__ float waveSum(float p) {
#pragma unroll
  for (int off = 32; off >= 1; off >>= 1) p += __shfl_xor(p, off, 64);
  return p;
}
__device__ __forceinline__ float waveMax(float p) {
#pragma unroll
  for (int off = 32; off >= 1; off >>= 1) p = fmaxf(p, __shfl_xor(p, off, 64));
  return p;
}
__device__ __forceinline__ short f2bf(float f) {
  __hip_bfloat16 h = __float2bfloat16(f);     // RNE; pairs fuse to v_cvt_pk_bf16_f32
  return __builtin_bit_cast(short, h);
}
__device__ __forceinline__ void gload_lds16(const void* g, void* l) {
  __builtin_amdgcn_global_load_lds(
      (const __attribute__((address_space(1))) u32*)g,
      (__attribute__((address_space(3))) u32*)l, 16, 0, 0);
}
// x[e] = bf16( av[e] * f32(b[e]) )  -- 8-element chunk, in registers
__device__ __forceinline__ bf16x8 prodcvt(const float* av, bf16x8 b) {
  u32x4 u = __builtin_bit_cast(u32x4, b);
  bf16x8 r;
#pragma unroll
  for (int p = 0; p < 4; ++p) {
    const float blo = __builtin_bit_cast(float, u[p] << 16);
    const float bhi = __builtin_bit_cast(float, u[p] & 0xffff0000u);
    r[2 * p]     = f2bf(av[2 * p]     * blo);
    r[2 * p + 1] = f2bf(av[2 * p + 1] * bhi);
  }
  return r;
}

// ---------------- K1 (fused): scores blocks [0,250) | Wt transpose blocks [250,442) ----------------
// scores: relu(V @ Wm1 + bm1) @ wm2 + bm2, 8 rows/block, 512 threads.
// wt: Wt[n][k] = bf16(Wab[k][n]), 64x64 tiles (12x16 tiles appended on grid.x).
__global__ __launch_bounds__(512) void scores_wt_kernel(
    const float* __restrict__ vectors, const float* __restrict__ Wm1,
    const float* __restrict__ bm1, const float* __restrict__ wm2,
    const float* __restrict__ bm2, const float* __restrict__ Wp1,
    float* __restrict__ scores, ushort* __restrict__ Wt) {
  __shared__ __align__(16) char smem[8 * DD * 4];   // 24 KB, both roles
  __shared__ float red[8];
  const int tid = threadIdx.x;
  if (blockIdx.x < SCOREBLKS) {
    float* vrow = (float*)smem;
    const int base = blockIdx.x * 8;
    for (int idx = tid; idx < 8 * DD; idx += 512)
      vrow[idx] = vectors[base * DD + idx];
    __syncthreads();
    float acc[8][2];
#pragma unroll
    for (int r = 0; r < 8; ++r) { acc[r][0] = 0.f; acc[r][1] = 0.f; }
#pragma unroll 4
    for (int d = 0; d < DD; ++d) {
      const float2 w = ((const float2*)(Wm1 + (size_t)d * HH))[tid];
#pragma unroll
      for (int r = 0; r < 8; ++r) {
        const float a = vrow[r * DD + d];
        acc[r][0] += a * w.x; acc[r][1] += a * w.y;
      }
    }
    const float2 b = ((const float2*)bm1)[tid];
    const float2 m = ((const float2*)wm2)[tid];
    const float sc = bm2[0];
    for (int r = 0; r < 8; ++r) {
      float p = fmaxf(acc[r][0] + b.x, 0.f) * m.x + fmaxf(acc[r][1] + b.y, 0.f) * m.y;
      p = waveSum(p);
      if ((tid & 63) == 0) red[tid >> 6] = p;
      __syncthreads();
      if (tid == 0) {
        float t = red[0];
#pragma unroll
        for (int w8 = 1; w8 < 8; ++w8) t += red[w8];
        scores[base + r] = t + sc;
      }
      __syncthreads();
    }
  } else {
    // ---- Wt transpose tile ----
    float (*tile)[65] = (float(*)[65])smem;           // 64x65 f32 = 16.6 KB
    const int t2 = blockIdx.x - SCOREBLKS;            // 0..191
    const int kb = t2 % 12;
    const int nb = t2 / 12;
    const float* Wab = Wp1 + 2 * DD * HH;
    for (int idx = tid; idx < 64 * 64; idx += 512) {
      const int kk = idx >> 6, nn = idx & 63;
      tile[kk][nn] = Wab[(size_t)(kb * 64 + kk) * HH + nb * 64 + nn];
    }
    __syncthreads();
    for (int idx = tid; idx < 64 * 64; idx += 512) {
      const int nn = idx >> 6, kk = idx & 63;
      Wt[(size_t)(nb * 64 + nn) * DD + kb * 64 + kk] = (ushort)f2bf(tile[kk][nn]);
    }
  }
}

// ---------------- K2: merged top-400 bitonic sort + lexsort (1 block) ----------------
__global__ __launch_bounds__(1024) void sort_kernel(
    const float* __restrict__ scores, const int* __restrict__ sst,
    const int* __restrict__ sen, int* __restrict__ perm,
    float* __restrict__ sfin) {
  __shared__ float ks[2048];
  __shared__ int   ki[2048];
  __shared__ int s_st[512], s_en[512], s_j[512];
  const int tid = threadIdx.x;
  for (int e = tid; e < 2048; e += 1024) {
    ks[e] = (e < NVEC) ? scores[e] : -INFINITY;
    ki[e] = e;
  }
  __syncthreads();
  for (int k = 2; k <= 2048; k <<= 1) {
    for (int j = k >> 1; j > 0; j >>= 1) {
      for (int e = tid; e < 2048; e += 1024) {
        const int l = e ^ j;
        if (l > e) {
          const float s1 = ks[e], s2 = ks[l];
          const int i1 = ki[e], i2 = ki[l];
          const bool first = (s1 > s2) || (s1 == s2 && i1 < i2);
          const bool up = ((e & k) == 0);
          if (up ? !first : first) {
            ks[e] = s2; ks[l] = s1; ki[e] = i2; ki[l] = i1;
          }
        }
      }
      __syncthreads();
    }
  }
  for (int e = tid; e < 512; e += 1024) {
    if (e < MSEL) { const int ti = ki[e]; s_st[e] = sst[ti]; s_en[e] = sen[ti]; }
    else { s_st[e] = 0x7fffffff; s_en[e] = 0x7fffffff; }
    s_j[e] = e;
  }
  __syncthreads();
  for (int k = 2; k <= 512; k <<= 1) {
    for (int j = k >> 1; j > 0; j >>= 1) {
      for (int e = tid; e < 512; e += 1024) {
        const int l = e ^ j;
        if (l > e) {
          const int a0 = s_st[e], a1 = s_en[e], a2 = s_j[e];
          const int b0 = s_st[l], b1 = s_en[l], b2 = s_j[l];
          const bool first = (a0 < b0) || (a0 == b0 && (a1 < b1 || (a1 == b1 && a2 < b2)));
          const bool up = ((e & k) == 0);
          if (up ? !first : first) {
            s_st[e] = b0; s_en[e] = b1; s_j[e] = b2;
            s_st[l] = a0; s_en[l] = a1; s_j[l] = a2;
          }
        }
      }
      __syncthreads();
    }
  }
  for (int i = tid; i < MSEL; i += 1024) {
    const int src = s_j[MSEL - 1 - i];
    const int vi = ki[src];
    perm[i] = vi;
    sfin[i] = scores[vi];
  }
}

// ---------------- K4: Ha = v@Wa, Hv = v@Wb; gather Vp (f32) + Vpb (bf16) ----------------
__global__ __launch_bounds__(256) void hab_kernel(
    const float* __restrict__ vectors, const float* __restrict__ Wp1,
    const int* __restrict__ perm, float* __restrict__ Ha, float* __restrict__ Hv,
    float* __restrict__ Vp, ushort* __restrict__ Vpb) {
  __shared__ float vrow[8 * DD];
  const int tid = threadIdx.x;
  const int base = blockIdx.x * 8;
  const int mat = blockIdx.y >> 1;       // 0 = Wa, 1 = Wb
  const int half = blockIdx.y & 1;       // col half
  for (int r = 0; r < 8; ++r) {
    const int pi = perm[base + r];
    for (int d = tid; d < DD; d += 256) {
      const float val = vectors[pi * DD + d];
      vrow[r * DD + d] = val;
      if (blockIdx.y == 0) {
        Vp[(size_t)(base + r) * DD + d] = val;
        Vpb[(size_t)(base + r) * DD + d] = (ushort)f2bf(val);
      }
    }
  }
  __syncthreads();
  float acc[8][2];
#pragma unroll
  for (int r = 0; r < 8; ++r) { acc[r][0] = 0.f; acc[r][1] = 0.f; }
  const float* W = Wp1 + (size_t)mat * DD * HH + half * 512;
#pragma unroll 4
  for (int d = 0; d < DD; ++d) {
    const float2 w = ((const float2*)(W + (size_t)d * HH))[tid];
#pragma unroll
    for (int r = 0; r < 8; ++r) {
      const float a = vrow[r * DD + d];
      acc[r][0] += a * w.x; acc[r][1] += a * w.y;
    }
  }
  float* dst = mat ? Hv : Ha;
  for (int r = 0; r < 8; ++r) {
    const int row = base + r;
    if (mat == 0 && row >= MR) continue;
    ((float2*)(dst + (size_t)row * HH + half * 512))[tid] =
        make_float2(acc[r][0], acc[r][1]);
  }
}

// ---------------- K5: pairwise einsum GEMM, 128x256 tile, 8 waves, 16 waves/CU (r15 best) ----------------
__global__ __launch_bounds__(512, 2) void pair_kernel(
    const float* __restrict__ Vp, const ushort* __restrict__ Vpb,
    const ushort* __restrict__ Wt,
    const float* __restrict__ bp1, const float* __restrict__ wp2,
    const float* __restrict__ Ha, const float* __restrict__ Hv,
    float* __restrict__ pp) {
  __shared__ __align__(16) ushort As[BM * BK];      // 16 KB
  __shared__ __align__(16) ushort Bs[BN * BK];      // 32 KB
  __shared__ float redp[BM][4];                     // 2 KB
  const int tid = threadIdx.x;
  const int mb = blockIdx.x;          // 0..797  (i*2 + khalf)
  const int nb = blockIdx.y;          // 0..3
  const int i = mb >> 1;
  const int khalf = mb & 1;
  const int n0 = nb * BN;
  const int lane = tid & 63;
  const int wid = tid >> 6;           // 0..7
  const int wr = wid >> 2, wc = wid & 3;
  const int lhi = lane >> 4, llo = lane & 15;

  // ---- stage geometry ----
  const int cs = tid & 7;
  const int rb9 = tid >> 3;                   // 0..63
  const int csx = cs ^ (rb9 & 7);             // same for both A chunks
  const ushort* vsrc[2];
  int rowA[2];
#pragma unroll
  for (int it = 0; it < 2; ++it) {
    rowA[it] = it * 64 + rb9;                 // 0..127
    int j = i + 1 + khalf * BM + rowA[it];
    if (j > MR) j = MR;
    vsrc[it] = Vpb + (size_t)j * DD + cs * 8;
  }
  int rowB[4];
#pragma unroll
  for (int it = 0; it < 4; ++it) rowB[it] = it * 64 + rb9;   // 0..255
  const float* avp = Vp + (size_t)i * DD + cs * 8;   // L1-hot row i

  f32x4 acc[4][4];
#pragma unroll
  for (int a = 0; a < 4; ++a)
#pragma unroll
    for (int b = 0; b < 4; ++b) acc[a][b] = (f32x4){0.f, 0.f, 0.f, 0.f};

  for (int kt = 0; kt < NKT; ++kt) {
    const int kg = kt * BK;
    // ---- stage phase: A-src loads FIRST (oldest VMEM), then B-DMAs, then prodcvt ----
    bf16x8 bv[2];
    float av[8];
#pragma unroll
    for (int it = 0; it < 2; ++it) bv[it] = *(const bf16x8*)(vsrc[it] + kg);
    *(float4*)(av) = *(const float4*)(avp + kg);
    *(float4*)(av + 4) = *(const float4*)(avp + kg + 4);
#pragma unroll
    for (int it = 0; it < 4; ++it)
      gload_lds16(Wt + (size_t)(n0 + rowB[it]) * DD + kg + csx * 8,
                  (char*)Bs + (it * 512 + tid) * 16);
#pragma unroll
    for (int it = 0; it < 2; ++it)
      *(bf16x8*)((char*)As + rowA[it] * 128 + (csx << 4)) = prodcvt(av, bv[it]);
    __syncthreads();   // drains DMA writes + A ds_writes
    // ---- compute phase: 2 k-steps of 32; 4x4 fragments per wave ----
#pragma unroll
    for (int ks = 0; ks < 2; ++ks) {
      bf16x8 af[4], bfr[4];
#pragma unroll
      for (int mi = 0; mi < 4; ++mi) {
        const int row = wr * 64 + mi * 16 + llo;
        const int ch = (ks * 4 + lhi) ^ (row & 7);
        af[mi] = *(const bf16x8*)((const char*)As + row * 128 + (ch << 4));
      }
#pragma unroll
      for (int ni = 0; ni < 4; ++ni) {
        const int row = wc * 64 + ni * 16 + llo;
        const int ch = (ks * 4 + lhi) ^ (row & 7);
        bfr[ni] = *(const bf16x8*)((const char*)Bs + row * 128 + (ch << 4));
      }
#pragma unroll
      for (int mi = 0; mi < 4; ++mi)
#pragma unroll
        for (int ni = 0; ni < 4; ++ni)
          acc[mi][ni] = __builtin_amdgcn_mfma_f32_16x16x32_bf16(af[mi], bfr[ni], acc[mi][ni], 0, 0, 0);
    }
    __syncthreads();   // all reads done before next stage overwrites
  }

  // ---- epilogue: relu(acc + Ha_i + Hv_j + bp1) . wp2 over this wave's 64 cols ----
  float hb4[4], wpv[4];
  int cg[4];
#pragma unroll
  for (int ni = 0; ni < 4; ++ni) {
    const int col = n0 + wc * 64 + ni * 16 + llo;
    cg[ni] = col;
    hb4[ni] = Ha[(size_t)i * HH + col] + bp1[col];
    wpv[ni] = wp2[col];
  }
#pragma unroll
  for (int mi = 0; mi < 4; ++mi) {
#pragma unroll
    for (int r = 0; r < 4; ++r) {
      const int rowl = wr * 64 + mi * 16 + lhi * 4 + r;
      int j = i + 1 + khalf * BM + rowl;
      if (j > MR) j = MR;
      float part = 0.f;
#pragma unroll
      for (int ni = 0; ni < 4; ++ni) {
        const float pre = acc[mi][ni][r] + hb4[ni] + Hv[(size_t)j * HH + cg[ni]];
        part += fmaxf(pre, 0.f) * wpv[ni];
      }
      part += __shfl_xor(part, 1, 64);
      part += __shfl_xor(part, 2, 64);
      part += __shfl_xor(part, 4, 64);
      part += __shfl_xor(part, 8, 64);
      if (llo == 0) redp[rowl][wc] = part;   // per-wave column-quarter partial
    }
  }
  __syncthreads();
  if (tid < BM)
    pp[(size_t)nb * NPAIR + (size_t)i * PPAD + khalf * BM + tid] =
        redp[tid][0] + redp[tid][1] + redp[tid][2] + redp[tid][3];
}

// ---------------- K6: sum partials + bias + scores, mask, softmax over 251 ----------------
__global__ __launch_bounds__(256) void softmax_kernel(
    const float* __restrict__ pp, const float* __restrict__ sfin,
    const float* __restrict__ bp2, float* __restrict__ out) {
  __shared__ float red[4];
  const int i = blockIdx.x, tid = threadIdx.x;
  float v;
  if (tid < KNUM) {
    const int jidx = i + 1 + tid;
    const bool valid = jidx < MSEL;
    const int jc = valid ? jidx : MR;
    float s = 0.f;
#pragma unroll
    for (int b = 0; b < NNB; ++b) s += pp[(size_t)b * NPAIR + i * PPAD + tid];
    v = valid ? (s + bp2[0] + sfin[jc] + sfin[i]) : -INFINITY;
  } else if (tid == KNUM) v = 0.f;
  else v = -INFINITY;
  float mx = waveMax(v);
  if ((tid & 63) == 0) red[tid >> 6] = mx;
  __syncthreads();
  const float m = fmaxf(fmaxf(red[0], red[1]), fmaxf(red[2], red[3]));
  __syncthreads();
  const float e = (tid <= KNUM) ? expf(v - m) : 0.f;
  float s = waveSum(e);
  if ((tid & 63) == 0) red[tid >> 6] = s;
  __syncthreads();
  const float tot = red[0] + red[1] + red[2] + red[3];
  if (tid <= KNUM) out[i * OUTW + tid] = e / tot;
}

extern "C" void kernel_launch(void* const* d_in, const int* in_sizes, int n_in,
                              void* d_out, int out_size, void* d_ws, size_t ws_size,
                              hipStream_t stream) {
  const float* vectors = (const float*)d_in[0];
  const float* Wm1 = (const float*)d_in[1];
  const float* bm1 = (const float*)d_in[2];
  const float* wm2 = (const float*)d_in[3];
  const float* bm2 = (const float*)d_in[4];
  const float* Wp1 = (const float*)d_in[5];
  const float* bp1 = (const float*)d_in[6];
  const float* wp2 = (const float*)d_in[7];
  const float* bp2 = (const float*)d_in[8];
  const int* sst = (const int*)d_in[9];
  const int* sen = (const int*)d_in[10];
  float* out = (float*)d_out;
  char* ws = (char*)d_ws;

  float* scores = (float*)(ws);                          // 2000 f32
  int*   perm   = (int*)(ws + 10240);                    // 400 i32
  float* sfin   = (float*)(ws + 12288);                  // 400 f32
  float* Ha     = (float*)(ws + 16384);                  // 400*1024 f32
  float* Hv     = (float*)(ws + 16384 + 1638400);        // 400*1024 f32
  float* Vp     = (float*)(ws + 3293184);                // 400*768 f32
  ushort* Wt    = (ushort*)(ws + 4521984);               // 1024*768 bf16
  ushort* Vpb   = (ushort*)(ws + 6094848);               // 400*768 bf16
  float* pp     = (float*)(ws + 6709248);                // 4 * 102144 f32 partials

  scores_wt_kernel<<<SCOREBLKS + 192, 512, 0, stream>>>(
      vectors, Wm1, bm1, wm2, bm2, Wp1, scores, Wt);
  sort_kernel<<<1, 1024, 0, stream>>>(scores, sst, sen, perm, sfin);
  hab_kernel<<<dim3(MSEL / 8, 4), 256, 0, stream>>>(vectors, Wp1, perm, Ha, Hv, Vp, Vpb);
  pair_kernel<<<dim3(MR * 2, NNB), 512, 0, stream>>>(Vp, Vpb, Wt, bp1, wp2, Ha, Hv, pp);
  softmax_kernel<<<MR, 256, 0, stream>>>(pp, sfin, bp2, out);
}

// Round 18
// 363.322 us; speedup vs baseline: 1.3319x; 1.0692x over previous
//
#include <hip/hip_runtime.h>
#include <hip/hip_bf16.h>
#include <math.h>

#define NVEC 2000
#define DD   768
#define HH   1024
#define KNUM 250
#define MSEL 400
#define MR   399     // m-1 rows
#define OUTW 251
#define PPAD 256                 // padded antecedents per anaphor
#define NPAIR (MR * PPAD)        // 102144 padded pair rows
#define BM 128
#define BN 256
#define BK 64
#define NKT (DD / BK)            // 12
#define NNB (HH / BN)            // 4
#define SCOREBLKS (NVEC / 8)     // 250
#define KH1 271                  // khalf=1 blocks exist only for i <= 270 (else fully masked)
#define PAIRBLKS (MR + KH1)      // 670 (was 798: 16% dead blocks removed)

typedef short  bf16x8 __attribute__((ext_vector_type(8)));
typedef float  f32x4  __attribute__((ext_vector_type(4)));
typedef unsigned int u32;
typedef u32    u32x4  __attribute__((ext_vector_type(4)));

__device__ __forceinline__ float waveSum(float p) {
#pragma unroll
  for (int off = 32; off >= 1; off >>= 1) p += __shfl_xor(p, off, 64);
  return p;
}
__device__ __forceinline__ float waveMax(float p) {
#pragma unroll
  for (int off = 32; off >= 1; off >>= 1) p = fmaxf(p, __shfl_xor(p, off, 64));
  return p;
}
__device__ __forceinline__ short f2bf(float f) {
  __hip_bfloat16 h = __float2bfloat16(f);     // RNE; pairs fuse to v_cvt_pk_bf16_f32
  return __builtin_bit_cast(short, h);
}
__device__ __forceinline__ void gload_lds16(const void* g, void* l) {
  __builtin_amdgcn_global_load_lds(
      (const __attribute__((address_space(1))) u32*)g,
      (__attribute__((address_space(3))) u32*)l, 16, 0, 0);
}
// x[e] = bf16( av[e] * f32(b[e]) )  -- 8-element chunk, in registers
__device__ __forceinline__ bf16x8 prodcvt(const float* av, bf16x8 b) {
  u32x4 u = __builtin_bit_cast(u32x4, b);
  bf16x8 r;
#pragma unroll
  for (int p = 0; p < 4; ++p) {
    const float blo = __builtin_bit_cast(float, u[p] << 16);
    const float bhi = __builtin_bit_cast(float, u[p] & 0xffff0000u);
    r[2 * p]     = f2bf(av[2 * p]     * blo);
    r[2 * p + 1] = f2bf(av[2 * p + 1] * bhi);
  }
  return r;
}

// ---------------- K1 (fused): scores blocks [0,250) | Wt transpose blocks [250,442) ----------------
__global__ __launch_bounds__(512) void scores_wt_kernel(
    const float* __restrict__ vectors, const float* __restrict__ Wm1,
    const float* __restrict__ bm1, const float* __restrict__ wm2,
    const float* __restrict__ bm2, const float* __restrict__ Wp1,
    float* __restrict__ scores, ushort* __restrict__ Wt) {
  __shared__ __align__(16) char smem[8 * DD * 4];   // 24 KB, both roles
  __shared__ float red[8];
  const int tid = threadIdx.x;
  if (blockIdx.x < SCOREBLKS) {
    float* vrow = (float*)smem;
    const int base = blockIdx.x * 8;
    for (int idx = tid; idx < 8 * DD; idx += 512)
      vrow[idx] = vectors[base * DD + idx];
    __syncthreads();
    float acc[8][2];
#pragma unroll
    for (int r = 0; r < 8; ++r) { acc[r][0] = 0.f; acc[r][1] = 0.f; }
#pragma unroll 4
    for (int d = 0; d < DD; ++d) {
      const float2 w = ((const float2*)(Wm1 + (size_t)d * HH))[tid];
#pragma unroll
      for (int r = 0; r < 8; ++r) {
        const float a = vrow[r * DD + d];
        acc[r][0] += a * w.x; acc[r][1] += a * w.y;
      }
    }
    const float2 b = ((const float2*)bm1)[tid];
    const float2 m = ((const float2*)wm2)[tid];
    const float sc = bm2[0];
    for (int r = 0; r < 8; ++r) {
      float p = fmaxf(acc[r][0] + b.x, 0.f) * m.x + fmaxf(acc[r][1] + b.y, 0.f) * m.y;
      p = waveSum(p);
      if ((tid & 63) == 0) red[tid >> 6] = p;
      __syncthreads();
      if (tid == 0) {
        float t = red[0];
#pragma unroll
        for (int w8 = 1; w8 < 8; ++w8) t += red[w8];
        scores[base + r] = t + sc;
      }
      __syncthreads();
    }
  } else {
    // ---- Wt transpose tile ----
    float (*tile)[65] = (float(*)[65])smem;           // 64x65 f32 = 16.6 KB
    const int t2 = blockIdx.x - SCOREBLKS;            // 0..191
    const int kb = t2 % 12;
    const int nb = t2 / 12;
    const float* Wab = Wp1 + 2 * DD * HH;
    for (int idx = tid; idx < 64 * 64; idx += 512) {
      const int kk = idx >> 6, nn = idx & 63;
      tile[kk][nn] = Wab[(size_t)(kb * 64 + kk) * HH + nb * 64 + nn];
    }
    __syncthreads();
    for (int idx = tid; idx < 64 * 64; idx += 512) {
      const int nn = idx >> 6, kk = idx & 63;
      Wt[(size_t)(nb * 64 + nn) * DD + kb * 64 + kk] = (ushort)f2bf(tile[kk][nn]);
    }
  }
}

// ---------------- K2: merged top-400 bitonic sort + lexsort (1 block) ----------------
__global__ __launch_bounds__(1024) void sort_kernel(
    const float* __restrict__ scores, const int* __restrict__ sst,
    const int* __restrict__ sen, int* __restrict__ perm,
    float* __restrict__ sfin) {
  __shared__ float ks[2048];
  __shared__ int   ki[2048];
  __shared__ int s_st[512], s_en[512], s_j[512];
  const int tid = threadIdx.x;
  for (int e = tid; e < 2048; e += 1024) {
    ks[e] = (e < NVEC) ? scores[e] : -INFINITY;
    ki[e] = e;
  }
  __syncthreads();
  for (int k = 2; k <= 2048; k <<= 1) {
    for (int j = k >> 1; j > 0; j >>= 1) {
      for (int e = tid; e < 2048; e += 1024) {
        const int l = e ^ j;
        if (l > e) {
          const float s1 = ks[e], s2 = ks[l];
          const int i1 = ki[e], i2 = ki[l];
          const bool first = (s1 > s2) || (s1 == s2 && i1 < i2);
          const bool up = ((e & k) == 0);
          if (up ? !first : first) {
            ks[e] = s2; ks[l] = s1; ki[e] = i2; ki[l] = i1;
          }
        }
      }
      __syncthreads();
    }
  }
  for (int e = tid; e < 512; e += 1024) {
    if (e < MSEL) { const int ti = ki[e]; s_st[e] = sst[ti]; s_en[e] = sen[ti]; }
    else { s_st[e] = 0x7fffffff; s_en[e] = 0x7fffffff; }
    s_j[e] = e;
  }
  __syncthreads();
  for (int k = 2; k <= 512; k <<= 1) {
    for (int j = k >> 1; j > 0; j >>= 1) {
      for (int e = tid; e < 512; e += 1024) {
        const int l = e ^ j;
        if (l > e) {
          const int a0 = s_st[e], a1 = s_en[e], a2 = s_j[e];
          const int b0 = s_st[l], b1 = s_en[l], b2 = s_j[l];
          const bool first = (a0 < b0) || (a0 == b0 && (a1 < b1 || (a1 == b1 && a2 < b2)));
          const bool up = ((e & k) == 0);
          if (up ? !first : first) {
            s_st[e] = b0; s_en[e] = b1; s_j[e] = b2;
            s_st[l] = a0; s_en[l] = a1; s_j[l] = a2;
          }
        }
      }
      __syncthreads();
    }
  }
  for (int i = tid; i < MSEL; i += 1024) {
    const int src = s_j[MSEL - 1 - i];
    const int vi = ki[src];
    perm[i] = vi;
    sfin[i] = scores[vi];
  }
}

// ---------------- K4: Ha = v@Wa, Hv = v@Wb; gather Vp (f32) + Vpb (bf16) ----------------
__global__ __launch_bounds__(256) void hab_kernel(
    const float* __restrict__ vectors, const float* __restrict__ Wp1,
    const int* __restrict__ perm, float* __restrict__ Ha, float* __restrict__ Hv,
    float* __restrict__ Vp, ushort* __restrict__ Vpb) {
  __shared__ float vrow[8 * DD];
  const int tid = threadIdx.x;
  const int base = blockIdx.x * 8;
  const int mat = blockIdx.y >> 1;       // 0 = Wa, 1 = Wb
  const int half = blockIdx.y & 1;       // col half
  for (int r = 0; r < 8; ++r) {
    const int pi = perm[base + r];
    for (int d = tid; d < DD; d += 256) {
      const float val = vectors[pi * DD + d];
      vrow[r * DD + d] = val;
      if (blockIdx.y == 0) {
        Vp[(size_t)(base + r) * DD + d] = val;
        Vpb[(size_t)(base + r) * DD + d] = (ushort)f2bf(val);
      }
    }
  }
  __syncthreads();
  float acc[8][2];
#pragma unroll
  for (int r = 0; r < 8; ++r) { acc[r][0] = 0.f; acc[r][1] = 0.f; }
  const float* W = Wp1 + (size_t)mat * DD * HH + half * 512;
#pragma unroll 4
  for (int d = 0; d < DD; ++d) {
    const float2 w = ((const float2*)(W + (size_t)d * HH))[tid];
#pragma unroll
    for (int r = 0; r < 8; ++r) {
      const float a = vrow[r * DD + d];
      acc[r][0] += a * w.x; acc[r][1] += a * w.y;
    }
  }
  float* dst = mat ? Hv : Ha;
  for (int r = 0; r < 8; ++r) {
    const int row = base + r;
    if (mat == 0 && row >= MR) continue;
    ((float2*)(dst + (size_t)row * HH + half * 512))[tid] =
        make_float2(acc[r][0], acc[r][1]);
  }
}

// ---------------- K5: pairwise einsum GEMM, 128x256 tile; dead khalf=1 blocks removed ----------------
// bx < MR: (i=bx, khalf=0). bx >= MR: (i=bx-MR, khalf=1) with i <= 270 (all rows
// valid-capable); khalf=1 blocks for i > 270 are fully masked by softmax -> skipped.
__global__ __launch_bounds__(512, 2) void pair_kernel(
    const float* __restrict__ Vp, const ushort* __restrict__ Vpb,
    const ushort* __restrict__ Wt,
    const float* __restrict__ bp1, const float* __restrict__ wp2,
    const float* __restrict__ Ha, const float* __restrict__ Hv,
    float* __restrict__ pp) {
  __shared__ __align__(16) ushort As[BM * BK];      // 16 KB
  __shared__ __align__(16) ushort Bs[BN * BK];      // 32 KB
  __shared__ float redp[BM][4];                     // 2 KB
  const int tid = threadIdx.x;
  const int bx = blockIdx.x;          // 0..669
  const int khalf = (bx < MR) ? 0 : 1;
  const int i = (bx < MR) ? bx : (bx - MR);
  const int nb = blockIdx.y;          // 0..3
  const int n0 = nb * BN;
  const int lane = tid & 63;
  const int wid = tid >> 6;           // 0..7
  const int wr = wid >> 2, wc = wid & 3;
  const int lhi = lane >> 4, llo = lane & 15;

  // ---- stage geometry ----
  const int cs = tid & 7;
  const int rb9 = tid >> 3;                   // 0..63
  const int csx = cs ^ (rb9 & 7);             // same for both A chunks
  const ushort* vsrc[2];
  int rowA[2];
#pragma unroll
  for (int it = 0; it < 2; ++it) {
    rowA[it] = it * 64 + rb9;                 // 0..127
    int j = i + 1 + khalf * BM + rowA[it];
    if (j > MR) j = MR;
    vsrc[it] = Vpb + (size_t)j * DD + cs * 8;
  }
  int rowB[4];
#pragma unroll
  for (int it = 0; it < 4; ++it) rowB[it] = it * 64 + rb9;   // 0..255
  const float* avp = Vp + (size_t)i * DD + cs * 8;   // L1-hot row i

  f32x4 acc[4][4];
#pragma unroll
  for (int a = 0; a < 4; ++a)
#pragma unroll
    for (int b = 0; b < 4; ++b) acc[a][b] = (f32x4){0.f, 0.f, 0.f, 0.f};

  for (int kt = 0; kt < NKT; ++kt) {
    const int kg = kt * BK;
    // ---- stage phase: A-src loads FIRST (oldest VMEM), then B-DMAs, then prodcvt ----
    bf16x8 bv[2];
    float av[8];
#pragma unroll
    for (int it = 0; it < 2; ++it) bv[it] = *(const bf16x8*)(vsrc[it] + kg);
    *(float4*)(av) = *(const float4*)(avp + kg);
    *(float4*)(av + 4) = *(const float4*)(avp + kg + 4);
#pragma unroll
    for (int it = 0; it < 4; ++it)
      gload_lds16(Wt + (size_t)(n0 + rowB[it]) * DD + kg + csx * 8,
                  (char*)Bs + (it * 512 + tid) * 16);
#pragma unroll
    for (int it = 0; it < 2; ++it)
      *(bf16x8*)((char*)As + rowA[it] * 128 + (csx << 4)) = prodcvt(av, bv[it]);
    __syncthreads();   // drains DMA writes + A ds_writes
    // ---- compute phase: 2 k-steps of 32; 4x4 fragments per wave ----
#pragma unroll
    for (int ks = 0; ks < 2; ++ks) {
      bf16x8 af[4], bfr[4];
#pragma unroll
      for (int mi = 0; mi < 4; ++mi) {
        const int row = wr * 64 + mi * 16 + llo;
        const int ch = (ks * 4 + lhi) ^ (row & 7);
        af[mi] = *(const bf16x8*)((const char*)As + row * 128 + (ch << 4));
      }
#pragma unroll
      for (int ni = 0; ni < 4; ++ni) {
        const int row = wc * 64 + ni * 16 + llo;
        const int ch = (ks * 4 + lhi) ^ (row & 7);
        bfr[ni] = *(const bf16x8*)((const char*)Bs + row * 128 + (ch << 4));
      }
#pragma unroll
      for (int mi = 0; mi < 4; ++mi)
#pragma unroll
        for (int ni = 0; ni < 4; ++ni)
          acc[mi][ni] = __builtin_amdgcn_mfma_f32_16x16x32_bf16(af[mi], bfr[ni], acc[mi][ni], 0, 0, 0);
    }
    __syncthreads();   // all reads done before next stage overwrites
  }

  // ---- epilogue: relu(acc + Ha_i + Hv_j + bp1) . wp2 over this wave's 64 cols ----
  float hb4[4], wpv[4];
  int cg[4];
#pragma unroll
  for (int ni = 0; ni < 4; ++ni) {
    const int col = n0 + wc * 64 + ni * 16 + llo;
    cg[ni] = col;
    hb4[ni] = Ha[(size_t)i * HH + col] + bp1[col];
    wpv[ni] = wp2[col];
  }
#pragma unroll
  for (int mi = 0; mi < 4; ++mi) {
#pragma unroll
    for (int r = 0; r < 4; ++r) {
      const int rowl = wr * 64 + mi * 16 + lhi * 4 + r;
      int j = i + 1 + khalf * BM + rowl;
      if (j > MR) j = MR;
      float part = 0.f;
#pragma unroll
      for (int ni = 0; ni < 4; ++ni) {
        const float pre = acc[mi][ni][r] + hb4[ni] + Hv[(size_t)j * HH + cg[ni]];
        part += fmaxf(pre, 0.f) * wpv[ni];
      }
      part += __shfl_xor(part, 1, 64);
      part += __shfl_xor(part, 2, 64);
      part += __shfl_xor(part, 4, 64);
      part += __shfl_xor(part, 8, 64);
      if (llo == 0) redp[rowl][wc] = part;   // per-wave column-quarter partial
    }
  }
  __syncthreads();
  if (tid < BM)
    pp[(size_t)nb * NPAIR + (size_t)i * PPAD + khalf * BM + tid] =
        redp[tid][0] + redp[tid][1] + redp[tid][2] + redp[tid][3];
}

// ---------------- K6: sum partials + bias + scores, mask, softmax over 251 ----------------
__global__ __launch_bounds__(256) void softmax_kernel(
    const float* __restrict__ pp, const float* __restrict__ sfin,
    const float* __restrict__ bp2, float* __restrict__ out) {
  __shared__ float red[4];
  const int i = blockIdx.x, tid = threadIdx.x;
  float v;
  if (tid < KNUM) {
    const int jidx = i + 1 + tid;
    const bool valid = jidx < MSEL;
    const int jc = valid ? jidx : MR;
    float s = 0.f;
#pragma unroll
    for (int b = 0; b < NNB; ++b) s += pp[(size_t)b * NPAIR + i * PPAD + tid];
    v = valid ? (s + bp2[0] + sfin[jc] + sfin[i]) : -INFINITY;
  } else if (tid == KNUM) v = 0.f;
  else v = -INFINITY;
  float mx = waveMax(v);
  if ((tid & 63) == 0) red[tid >> 6] = mx;
  __syncthreads();
  const float m = fmaxf(fmaxf(red[0], red[1]), fmaxf(red[2], red[3]));
  __syncthreads();
  const float e = (tid <= KNUM) ? expf(v - m) : 0.f;
  float s = waveSum(e);
  if ((tid & 63) == 0) red[tid >> 6] = s;
  __syncthreads();
  const float tot = red[0] + red[1] + red[2] + red[3];
  if (tid <= KNUM) out[i * OUTW + tid] = e / tot;
}

extern "C" void kernel_launch(void* const* d_in, const int* in_sizes, int n_in,
                              void* d_out, int out_size, void* d_ws, size_t ws_size,
                              hipStream_t stream) {
  const float* vectors = (const float*)d_in[0];
  const float* Wm1 = (const float*)d_in[1];
  const float* bm1 = (const float*)d_in[2];
  const float* wm2 = (const float*)d_in[3];
  const float* bm2 = (const float*)d_in[4];
  const float* Wp1 = (const float*)d_in[5];
  const float* bp1 = (const float*)d_in[6];
  const float* wp2 = (const float*)d_in[7];
  const float* bp2 = (const float*)d_in[8];
  const int* sst = (const int*)d_in[9];
  const int* sen = (const int*)d_in[10];
  float* out = (float*)d_out;
  char* ws = (char*)d_ws;

  float* scores = (float*)(ws);                          // 2000 f32
  int*   perm   = (int*)(ws + 10240);                    // 400 i32
  float* sfin   = (float*)(ws + 12288);                  // 400 f32
  float* Ha     = (float*)(ws + 16384);                  // 400*1024 f32
  float* Hv     = (float*)(ws + 16384 + 1638400);        // 400*1024 f32
  float* Vp     = (float*)(ws + 3293184);                // 400*768 f32
  ushort* Wt    = (ushort*)(ws + 4521984);               // 1024*768 bf16
  ushort* Vpb   = (ushort*)(ws + 6094848);               // 400*768 bf16
  float* pp     = (float*)(ws + 6709248);                // 4 * 102144 f32 partials

  scores_wt_kernel<<<SCOREBLKS + 192, 512, 0, stream>>>(
      vectors, Wm1, bm1, wm2, bm2, Wp1, scores, Wt);
  sort_kernel<<<1, 1024, 0, stream>>>(scores, sst, sen, perm, sfin);
  hab_kernel<<<dim3(MSEL / 8, 4), 256, 0, stream>>>(vectors, Wp1, perm, Ha, Hv, Vp, Vpb);
  pair_kernel<<<dim3(PAIRBLKS, NNB), 512, 0, stream>>>(Vp, Vpb, Wt, bp1, wp2, Ha, Hv, pp);
  softmax_kernel<<<MR, 256, 0, stream>>>(pp, sfin, bp2, out);
}

// Round 19
// 356.724 us; speedup vs baseline: 1.3566x; 1.0185x over previous
//
#include <hip/hip_runtime.h>
#include <hip/hip_bf16.h>
#include <math.h>

#define NVEC 2000
#define DD   768
#define HH   1024
#define KNUM 250
#define MSEL 400
#define MR   399     // m-1 rows
#define OUTW 251
#define PPAD 256                 // padded antecedents per anaphor
#define NPAIR (MR * PPAD)        // 102144 padded pair rows
#define BM 128
#define BN 256
#define BK 64
#define NKT (DD / BK)            // 12
#define NNB (HH / BN)            // 4
#define KH1 271                  // khalf=1 blocks exist only for i <= 270 (else fully masked)
#define PAIRBLKS (MR + KH1)      // 670

typedef short  bf16x8 __attribute__((ext_vector_type(8)));
typedef float  f32x4  __attribute__((ext_vector_type(4)));
typedef unsigned int u32;
typedef u32    u32x4  __attribute__((ext_vector_type(4)));

__device__ __forceinline__ float waveSum(float p) {
#pragma unroll
  for (int off = 32; off >= 1; off >>= 1) p += __shfl_xor(p, off, 64);
  return p;
}
__device__ __forceinline__ float waveMax(float p) {
#pragma unroll
  for (int off = 32; off >= 1; off >>= 1) p = fmaxf(p, __shfl_xor(p, off, 64));
  return p;
}
__device__ __forceinline__ short f2bf(float f) {
  __hip_bfloat16 h = __float2bfloat16(f);     // RNE; pairs fuse to v_cvt_pk_bf16_f32
  return __builtin_bit_cast(short, h);
}
__device__ __forceinline__ void gload_lds16(const void* g, void* l) {
  __builtin_amdgcn_global_load_lds(
      (const __attribute__((address_space(1))) u32*)g,
      (__attribute__((address_space(3))) u32*)l, 16, 0, 0);
}
// x[e] = bf16( av[e] * f32(b[e]) )  -- 8-element chunk, in registers
__device__ __forceinline__ bf16x8 prodcvt(const float* av, bf16x8 b) {
  u32x4 u = __builtin_bit_cast(u32x4, b);
  bf16x8 r;
#pragma unroll
  for (int p = 0; p < 4; ++p) {
    const float blo = __builtin_bit_cast(float, u[p] << 16);
    const float bhi = __builtin_bit_cast(float, u[p] & 0xffff0000u);
    r[2 * p]     = f2bf(av[2 * p]     * blo);
    r[2 * p + 1] = f2bf(av[2 * p + 1] * bhi);
  }
  return r;
}

// ---------------- K1: scores = relu(V @ Wm1 + bm1) @ wm2 + bm2 (250 blocks) ----------------
__global__ __launch_bounds__(512) void scores_kernel(
    const float* __restrict__ vectors, const float* __restrict__ Wm1,
    const float* __restrict__ bm1, const float* __restrict__ wm2,
    const float* __restrict__ bm2, float* __restrict__ scores) {
  __shared__ float vrow[8 * DD];
  __shared__ float red[8];
  const int tid = threadIdx.x;
  const int base = blockIdx.x * 8;
  for (int idx = tid; idx < 8 * DD; idx += 512)
    vrow[idx] = vectors[base * DD + idx];
  __syncthreads();
  float acc[8][2];
#pragma unroll
  for (int r = 0; r < 8; ++r) { acc[r][0] = 0.f; acc[r][1] = 0.f; }
#pragma unroll 4
  for (int d = 0; d < DD; ++d) {
    const float2 w = ((const float2*)(Wm1 + (size_t)d * HH))[tid];
#pragma unroll
    for (int r = 0; r < 8; ++r) {
      const float a = vrow[r * DD + d];
      acc[r][0] += a * w.x; acc[r][1] += a * w.y;
    }
  }
  const float2 b = ((const float2*)bm1)[tid];
  const float2 m = ((const float2*)wm2)[tid];
  const float sc = bm2[0];
  for (int r = 0; r < 8; ++r) {
    float p = fmaxf(acc[r][0] + b.x, 0.f) * m.x + fmaxf(acc[r][1] + b.y, 0.f) * m.y;
    p = waveSum(p);
    if ((tid & 63) == 0) red[tid >> 6] = p;
    __syncthreads();
    if (tid == 0) {
      float t = red[0];
#pragma unroll
      for (int w8 = 1; w8 < 8; ++w8) t += red[w8];
      scores[base + r] = t + sc;
    }
    __syncthreads();
  }
}

// ---------------- K2 (fused): block 0 = sort+lexsort | blocks 1..192 = Wt transpose ----------------
// Sort occupies one CU; the wt tiles fill the other 255 CUs concurrently (independent work).
__global__ __launch_bounds__(1024) void sortwt_kernel(
    const float* __restrict__ scores, const int* __restrict__ sst,
    const int* __restrict__ sen, const float* __restrict__ Wp1,
    int* __restrict__ perm, float* __restrict__ sfin, ushort* __restrict__ Wt) {
  const int tid = threadIdx.x;
  if (blockIdx.x == 0) {
    __shared__ float ks[2048];
    __shared__ int   ki[2048];
    __shared__ int s_st[512], s_en[512], s_j[512];
    for (int e = tid; e < 2048; e += 1024) {
      ks[e] = (e < NVEC) ? scores[e] : -INFINITY;
      ki[e] = e;
    }
    __syncthreads();
    for (int k = 2; k <= 2048; k <<= 1) {
      for (int j = k >> 1; j > 0; j >>= 1) {
        for (int e = tid; e < 2048; e += 1024) {
          const int l = e ^ j;
          if (l > e) {
            const float s1 = ks[e], s2 = ks[l];
            const int i1 = ki[e], i2 = ki[l];
            const bool first = (s1 > s2) || (s1 == s2 && i1 < i2);
            const bool up = ((e & k) == 0);
            if (up ? !first : first) {
              ks[e] = s2; ks[l] = s1; ki[e] = i2; ki[l] = i1;
            }
          }
        }
        __syncthreads();
      }
    }
    for (int e = tid; e < 512; e += 1024) {
      if (e < MSEL) { const int ti = ki[e]; s_st[e] = sst[ti]; s_en[e] = sen[ti]; }
      else { s_st[e] = 0x7fffffff; s_en[e] = 0x7fffffff; }
      s_j[e] = e;
    }
    __syncthreads();
    for (int k = 2; k <= 512; k <<= 1) {
      for (int j = k >> 1; j > 0; j >>= 1) {
        for (int e = tid; e < 512; e += 1024) {
          const int l = e ^ j;
          if (l > e) {
            const int a0 = s_st[e], a1 = s_en[e], a2 = s_j[e];
            const int b0 = s_st[l], b1 = s_en[l], b2 = s_j[l];
            const bool first = (a0 < b0) || (a0 == b0 && (a1 < b1 || (a1 == b1 && a2 < b2)));
            const bool up = ((e & k) == 0);
            if (up ? !first : first) {
              s_st[e] = b0; s_en[e] = b1; s_j[e] = b2;
              s_st[l] = a0; s_en[l] = a1; s_j[l] = a2;
            }
          }
        }
        __syncthreads();
      }
    }
    for (int i = tid; i < MSEL; i += 1024) {
      const int src = s_j[MSEL - 1 - i];
      const int vi = ki[src];
      perm[i] = vi;
      sfin[i] = scores[vi];
    }
  } else {
    // ---- Wt transpose tile: Wt[n][k] = bf16(Wab[k][n]) ----
    __shared__ float tile[64][65];
    const int t2 = blockIdx.x - 1;            // 0..191
    const int kb = t2 % 12;
    const int nb = t2 / 12;
    const float* Wab = Wp1 + 2 * DD * HH;
    for (int idx = tid; idx < 64 * 64; idx += 1024) {
      const int kk = idx >> 6, nn = idx & 63;
      tile[kk][nn] = Wab[(size_t)(kb * 64 + kk) * HH + nb * 64 + nn];
    }
    __syncthreads();
    for (int idx = tid; idx < 64 * 64; idx += 1024) {
      const int nn = idx >> 6, kk = idx & 63;
      Wt[(size_t)(nb * 64 + nn) * DD + kb * 64 + kk] = (ushort)f2bf(tile[kk][nn]);
    }
  }
}

// ---------------- K3: Ha = v@Wa, Hv = v@Wb; gather Vp (f32) + Vpb (bf16) ----------------
// 512 threads (8 waves -> 2 waves/SIMD for latency hiding), 1 scalar col/thread.
__global__ __launch_bounds__(512) void hab_kernel(
    const float* __restrict__ vectors, const float* __restrict__ Wp1,
    const int* __restrict__ perm, float* __restrict__ Ha, float* __restrict__ Hv,
    float* __restrict__ Vp, ushort* __restrict__ Vpb) {
  __shared__ float vrow[8 * DD];
  const int tid = threadIdx.x;
  const int base = blockIdx.x * 8;
  const int mat = blockIdx.y >> 1;       // 0 = Wa, 1 = Wb
  const int half = blockIdx.y & 1;       // col half
  for (int r = 0; r < 8; ++r) {
    const int pi = perm[base + r];
    for (int d = tid; d < DD; d += 512) {
      const float val = vectors[pi * DD + d];
      vrow[r * DD + d] = val;
      if (blockIdx.y == 0) {
        Vp[(size_t)(base + r) * DD + d] = val;
        Vpb[(size_t)(base + r) * DD + d] = (ushort)f2bf(val);
      }
    }
  }
  __syncthreads();
  float acc[8];
#pragma unroll
  for (int r = 0; r < 8; ++r) acc[r] = 0.f;
  const float* W = Wp1 + (size_t)mat * DD * HH + half * 512 + tid;
#pragma unroll 4
  for (int d = 0; d < DD; ++d) {
    const float w = W[(size_t)d * HH];
#pragma unroll
    for (int r = 0; r < 8; ++r) acc[r] += vrow[r * DD + d] * w;
  }
  float* dst = mat ? Hv : Ha;
  for (int r = 0; r < 8; ++r) {
    const int row = base + r;
    if (mat == 0 && row >= MR) continue;
    dst[(size_t)row * HH + half * 512 + tid] = acc[r];
  }
}

// ---------------- K4: pairwise einsum GEMM, 128x256 tile; dead khalf=1 blocks removed ----------------
__global__ __launch_bounds__(512, 2) void pair_kernel(
    const float* __restrict__ Vp, const ushort* __restrict__ Vpb,
    const ushort* __restrict__ Wt,
    const float* __restrict__ bp1, const float* __restrict__ wp2,
    const float* __restrict__ Ha, const float* __restrict__ Hv,
    float* __restrict__ pp) {
  __shared__ __align__(16) ushort As[BM * BK];      // 16 KB
  __shared__ __align__(16) ushort Bs[BN * BK];      // 32 KB
  __shared__ float redp[BM][4];                     // 2 KB
  const int tid = threadIdx.x;
  const int bx = blockIdx.x;          // 0..669
  const int khalf = (bx < MR) ? 0 : 1;
  const int i = (bx < MR) ? bx : (bx - MR);
  const int nb = blockIdx.y;          // 0..3
  const int n0 = nb * BN;
  const int lane = tid & 63;
  const int wid = tid >> 6;           // 0..7
  const int wr = wid >> 2, wc = wid & 3;
  const int lhi = lane >> 4, llo = lane & 15;

  // ---- stage geometry ----
  const int cs = tid & 7;
  const int rb9 = tid >> 3;                   // 0..63
  const int csx = cs ^ (rb9 & 7);             // same for both A chunks
  const ushort* vsrc[2];
  int rowA[2];
#pragma unroll
  for (int it = 0; it < 2; ++it) {
    rowA[it] = it * 64 + rb9;                 // 0..127
    int j = i + 1 + khalf * BM + rowA[it];
    if (j > MR) j = MR;
    vsrc[it] = Vpb + (size_t)j * DD + cs * 8;
  }
  int rowB[4];
#pragma unroll
  for (int it = 0; it < 4; ++it) rowB[it] = it * 64 + rb9;   // 0..255
  const float* avp = Vp + (size_t)i * DD + cs * 8;   // L1-hot row i

  f32x4 acc[4][4];
#pragma unroll
  for (int a = 0; a < 4; ++a)
#pragma unroll
    for (int b = 0; b < 4; ++b) acc[a][b] = (f32x4){0.f, 0.f, 0.f, 0.f};

  for (int kt = 0; kt < NKT; ++kt) {
    const int kg = kt * BK;
    // ---- stage phase: A-src loads FIRST (oldest VMEM), then B-DMAs, then prodcvt ----
    bf16x8 bv[2];
    float av[8];
#pragma unroll
    for (int it = 0; it < 2; ++it) bv[it] = *(const bf16x8*)(vsrc[it] + kg);
    *(float4*)(av) = *(const float4*)(avp + kg);
    *(float4*)(av + 4) = *(const float4*)(avp + kg + 4);
#pragma unroll
    for (int it = 0; it < 4; ++it)
      gload_lds16(Wt + (size_t)(n0 + rowB[it]) * DD + kg + csx * 8,
                  (char*)Bs + (it * 512 + tid) * 16);
#pragma unroll
    for (int it = 0; it < 2; ++it)
      *(bf16x8*)((char*)As + rowA[it] * 128 + (csx << 4)) = prodcvt(av, bv[it]);
    __syncthreads();   // drains DMA writes + A ds_writes
    // ---- compute phase: 2 k-steps of 32; 4x4 fragments per wave ----
#pragma unroll
    for (int ks = 0; ks < 2; ++ks) {
      bf16x8 af[4], bfr[4];
#pragma unroll
      for (int mi = 0; mi < 4; ++mi) {
        const int row = wr * 64 + mi * 16 + llo;
        const int ch = (ks * 4 + lhi) ^ (row & 7);
        af[mi] = *(const bf16x8*)((const char*)As + row * 128 + (ch << 4));
      }
#pragma unroll
      for (int ni = 0; ni < 4; ++ni) {
        const int row = wc * 64 + ni * 16 + llo;
        const int ch = (ks * 4 + lhi) ^ (row & 7);
        bfr[ni] = *(const bf16x8*)((const char*)Bs + row * 128 + (ch << 4));
      }
#pragma unroll
      for (int mi = 0; mi < 4; ++mi)
#pragma unroll
        for (int ni = 0; ni < 4; ++ni)
          acc[mi][ni] = __builtin_amdgcn_mfma_f32_16x16x32_bf16(af[mi], bfr[ni], acc[mi][ni], 0, 0, 0);
    }
    __syncthreads();   // all reads done before next stage overwrites
  }

  // ---- epilogue: relu(acc + Ha_i + Hv_j + bp1) . wp2 over this wave's 64 cols ----
  float hb4[4], wpv[4];
  int cg[4];
#pragma unroll
  for (int ni = 0; ni < 4; ++ni) {
    const int col = n0 + wc * 64 + ni * 16 + llo;
    cg[ni] = col;
    hb4[ni] = Ha[(size_t)i * HH + col] + bp1[col];
    wpv[ni] = wp2[col];
  }
#pragma unroll
  for (int mi = 0; mi < 4; ++mi) {
#pragma unroll
    for (int r = 0; r < 4; ++r) {
      const int rowl = wr * 64 + mi * 16 + lhi * 4 + r;
      int j = i + 1 + khalf * BM + rowl;
      if (j > MR) j = MR;
      float part = 0.f;
#pragma unroll
      for (int ni = 0; ni < 4; ++ni) {
        const float pre = acc[mi][ni][r] + hb4[ni] + Hv[(size_t)j * HH + cg[ni]];
        part += fmaxf(pre, 0.f) * wpv[ni];
      }
      part += __shfl_xor(part, 1, 64);
      part += __shfl_xor(part, 2, 64);
      part += __shfl_xor(part, 4, 64);
      part += __shfl_xor(part, 8, 64);
      if (llo == 0) redp[rowl][wc] = part;   // per-wave column-quarter partial
    }
  }
  __syncthreads();
  if (tid < BM)
    pp[(size_t)nb * NPAIR + (size_t)i * PPAD + khalf * BM + tid] =
        redp[tid][0] + redp[tid][1] + redp[tid][2] + redp[tid][3];
}

// ---------------- K5: sum partials + bias + scores, mask, softmax over 251 ----------------
__global__ __launch_bounds__(256) void softmax_kernel(
    const float* __restrict__ pp, const float* __restrict__ sfin,
    const float* __restrict__ bp2, float* __restrict__ out) {
  __shared__ float red[4];
  const int i = blockIdx.x, tid = threadIdx.x;
  float v;
  if (tid < KNUM) {
    const int jidx = i + 1 + tid;
    const bool valid = jidx < MSEL;
    const int jc = valid ? jidx : MR;
    float s = 0.f;
#pragma unroll
    for (int b = 0; b < NNB; ++b) s += pp[(size_t)b * NPAIR + i * PPAD + tid];
    v = valid ? (s + bp2[0] + sfin[jc] + sfin[i]) : -INFINITY;
  } else if (tid == KNUM) v = 0.f;
  else v = -INFINITY;
  float mx = waveMax(v);
  if ((tid & 63) == 0) red[tid >> 6] = mx;
  __syncthreads();
  const float m = fmaxf(fmaxf(red[0], red[1]), fmaxf(red[2], red[3]));
  __syncthreads();
  const float e = (tid <= KNUM) ? expf(v - m) : 0.f;
  float s = waveSum(e);
  if ((tid & 63) == 0) red[tid >> 6] = s;
  __syncthreads();
  const float tot = red[0] + red[1] + red[2] + red[3];
  if (tid <= KNUM) out[i * OUTW + tid] = e / tot;
}

extern "C" void kernel_launch(void* const* d_in, const int* in_sizes, int n_in,
                              void* d_out, int out_size, void* d_ws, size_t ws_size,
                              hipStream_t stream) {
  const float* vectors = (const float*)d_in[0];
  const float* Wm1 = (const float*)d_in[1];
  const float* bm1 = (const float*)d_in[2];
  const float* wm2 = (const float*)d_in[3];
  const float* bm2 = (const float*)d_in[4];
  const float* Wp1 = (const float*)d_in[5];
  const float* bp1 = (const float*)d_in[6];
  const float* wp2 = (const float*)d_in[7];
  const float* bp2 = (const float*)d_in[8];
  const int* sst = (const int*)d_in[9];
  const int* sen = (const int*)d_in[10];
  float* out = (float*)d_out;
  char* ws = (char*)d_ws;

  float* scores = (float*)(ws);                          // 2000 f32
  int*   perm   = (int*)(ws + 10240);                    // 400 i32
  float* sfin   = (float*)(ws + 12288);                  // 400 f32
  float* Ha     = (float*)(ws + 16384);                  // 400*1024 f32
  float* Hv     = (float*)(ws + 16384 + 1638400);        // 400*1024 f32
  float* Vp     = (float*)(ws + 3293184);                // 400*768 f32
  ushort* Wt    = (ushort*)(ws + 4521984);               // 1024*768 bf16
  ushort* Vpb   = (ushort*)(ws + 6094848);               // 400*768 bf16
  float* pp     = (float*)(ws + 6709248);                // 4 * 102144 f32 partials

  scores_kernel<<<NVEC / 8, 512, 0, stream>>>(vectors, Wm1, bm1, wm2, bm2, scores);
  sortwt_kernel<<<193, 1024, 0, stream>>>(scores, sst, sen, Wp1, perm, sfin, Wt);
  hab_kernel<<<dim3(MSEL / 8, 4), 512, 0, stream>>>(vectors, Wp1, perm, Ha, Hv, Vp, Vpb);
  pair_kernel<<<dim3(PAIRBLKS, NNB), 512, 0, stream>>>(Vp, Vpb, Wt, bp1, wp2, Ha, Hv, pp);
  softmax_kernel<<<MR, 256, 0, stream>>>(pp, sfin, bp2, out);
}